// Round 1
// 583.000 us; speedup vs baseline: 1.0932x; 1.0932x over previous
//
#include <hip/hip_runtime.h>
#include <hip/hip_bf16.h>
#include <math.h>

typedef __hip_bfloat16 bf16;
typedef __attribute__((ext_vector_type(8))) short short8;
typedef __attribute__((ext_vector_type(4))) float f32x4;

// Problem constants
#define NB 4
#define NS 1024
#define ND 1024
#define NH 16
#define NDH 64
#define NR 64
#define NDFF 4096
#define NM (NB*NS)     // 4096 rows
#define NTOPK 204      // int(1024*0.2)

static __device__ __forceinline__ float b2f(bf16 x) { return __bfloat162float(x); }
static __device__ __forceinline__ bf16  f2b(float x) { return __float2bfloat16(x); }
static __device__ __forceinline__ unsigned short bfbits(float x) {
  bf16 h = __float2bfloat16(x);
  return *reinterpret_cast<unsigned short*>(&h);
}

// async global->LDS, 16B per lane; LDS dest = wave-uniform base + lane*16
static __device__ __forceinline__ void gload_lds16(const void* g, void* l) {
  __builtin_amdgcn_global_load_lds(
      (const __attribute__((address_space(1))) void*)g,
      (__attribute__((address_space(3))) void*)l, 16, 0, 0);
}

// 8 consecutive bf16 -> fp32 (one 16B load)
static __device__ __forceinline__ void ld8(const bf16* p, float* d) {
  const uint4 u = *(const uint4*)p;
  d[0] = __uint_as_float((u.x & 0xffffu) << 16);
  d[1] = __uint_as_float(u.x & 0xffff0000u);
  d[2] = __uint_as_float((u.y & 0xffffu) << 16);
  d[3] = __uint_as_float(u.y & 0xffff0000u);
  d[4] = __uint_as_float((u.z & 0xffffu) << 16);
  d[5] = __uint_as_float(u.z & 0xffff0000u);
  d[6] = __uint_as_float((u.w & 0xffffu) << 16);
  d[7] = __uint_as_float(u.w & 0xffff0000u);
}

static __device__ __forceinline__ float block_sum_256(float v, float* rbuf, int tid) {
  rbuf[tid] = v;
  __syncthreads();
  #pragma unroll
  for (int st = 128; st > 0; st >>= 1) {
    if (tid < st) rbuf[tid] += rbuf[tid + st];
    __syncthreads();
  }
  const float r = rbuf[0];
  __syncthreads();
  return r;
}

// ---------------------------------------------------------------------------
// fp32 -> bf16 cast (n multiple of 4)
// ---------------------------------------------------------------------------
__global__ __launch_bounds__(256) void cast_kernel(const float* __restrict__ in,
                                                   bf16* __restrict__ out, int n) {
  const int i = (blockIdx.x * 256 + threadIdx.x) * 4;
  if (i < n) {
    const float4 v = *(const float4*)(in + i);
    uint2 o;
    o.x = (unsigned)bfbits(v.x) | ((unsigned)bfbits(v.y) << 16);
    o.y = (unsigned)bfbits(v.z) | ((unsigned)bfbits(v.w) << 16);
    *(uint2*)(out + i) = o;
  }
}

// Concat Qp_w/Kp_w -> bf16 [128][1024], Qp_b/Kp_b -> fp32 [128]
__global__ __launch_bounds__(256) void pack_qk_kernel(
    const float* __restrict__ Qw, const float* __restrict__ Kw,
    const float* __restrict__ Qb, const float* __restrict__ Kb,
    bf16* __restrict__ w, float* __restrict__ bias) {
  const int r = blockIdx.x;  // 0..127
  const float* srcw = (r < 64) ? (Qw + (size_t)r * ND) : (Kw + (size_t)(r - 64) * ND);
  for (int i = threadIdx.x; i < ND; i += 256) w[(size_t)r * ND + i] = f2b(srcw[i]);
  if (r == 0)
    for (int i = threadIdx.x; i < 128; i += 256)
      bias[i] = (i < 64) ? Qb[i] : Kb[i - 64];
}

// ---------------------------------------------------------------------------
// Generic batched MFMA GEMM: C = scale*(A @ W^T) (+bias), bf16 in.
// Double-buffered BK-wide software pipeline (global_load_lds width=16).
// LDS slot-XOR swizzle: global_load_lds forces a LINEAR LDS destination, so
// the 16B-slot permutation is applied to the per-lane GLOBAL source column at
// stage time and undone at ds_read time (same involution both sides):
//   BK=32 (64B rows, banks alias every 2 rows): slot' = slot ^ ((row>>1)&3)
//   BK=64 (128B rows):                          slot' = slot ^ (row&7)
// -> fragment ds_read_b128 bank starts distinct within each 16-lane group
//    (2-way aliasing only = free), vs 8-way unswizzled.
// BK=64 doubles MFMAs per barrier phase (16) for the narrow 128x64 tile.
// 256 threads = 4 waves in a 2x2 grid; wave tile = (BM/2)x(BN/2).
// Batch z: off = (z>>4)*Hi + (z&15)*Lo.  K multiple of BK.
// XCD-compact swizzle when gridDim.x%8==0 (perf heuristic only).
// ---------------------------------------------------------------------------
template<int BM, int BN, int BK, int BIAS, int RELU, int OUTF32>
__global__ __launch_bounds__(256) void mfma_gemm(
    const bf16* __restrict__ A, const bf16* __restrict__ W,
    const float* __restrict__ bias, void* __restrict__ C,
    int K, int lda, int ldb, int ldc,
    long long aHi, long long aLo, long long bHi, long long bLo,
    long long cHi, long long cLo, float scale)
{
  constexpr int WTM = BM / 2;
  constexpr int WTN = BN / 2;
  constexpr int AM = WTM / 16;
  constexpr int AN = WTN / 16;
  constexpr int KK = BK / 32;        // MFMA sub-steps per K-tile
  constexpr int SLOTS = BK / 8;      // 16B slots per LDS row
  constexpr int RPC = 512 / BK;      // rows per wave per gload_lds16 call
  __shared__ short As[2][BM * BK];
  __shared__ short Bs[2][BN * BK];
  const int tid  = threadIdx.x;
  const int lane = tid & 63;
  const int w    = tid >> 6;
  const int z    = blockIdx.z;
  const long long aOff = (long long)(z >> 4) * aHi + (long long)(z & 15) * aLo;
  const long long bOff = (long long)(z >> 4) * bHi + (long long)(z & 15) * bLo;
  const long long cOff = (long long)(z >> 4) * cHi + (long long)(z & 15) * cLo;

  int bx = blockIdx.x, by = blockIdx.y;
  if ((gridDim.x & 7) == 0) {
    const unsigned lin = blockIdx.y * gridDim.x + blockIdx.x;
    const unsigned Wd = gridDim.x >> 3;
    const unsigned xcd = lin & 7, i = lin >> 3;
    bx = (int)(xcd * Wd + (i % Wd));
    by = (int)(i / Wd);
  }
  const int m0 = by * BM;
  const int n0 = bx * BN;
  const int wr = w >> 1, wc = w & 1;
  const int lm = lane & 15, quad = lane >> 4;

  f32x4 acc[AM][AN];
  #pragma unroll
  for (int i = 0; i < AM; ++i)
    #pragma unroll
    for (int j = 0; j < AN; ++j) acc[i][j] = (f32x4){0.f, 0.f, 0.f, 0.f};

  // staging lane map + slot swizzle (write side, applied to GLOBAL source col)
  const int slot = lane & (SLOTS - 1);
  const int sr   = lane / SLOTS;     // row within this wave's RPC-row chunk
  const int swz  = (BK == 32) ? ((sr >> 1) & 3) : (sr & 7);
  const int scol = (slot ^ swz) << 3;  // shorts
  // read-side swizzle (row == lm mod 16; chunk bases are slot-period aligned)
  const int xv   = (BK == 32) ? ((lm >> 1) & 3) : (lm & 7);
  const bf16* Ab = A + aOff;
  const bf16* Bb = W + bOff;

  auto stage = [&](int buf, int k0) {
    #pragma unroll
    for (int t = 0; t < (BM * BK) / 2048; ++t) {
      const int row = w * (BM / 4) + t * RPC;
      gload_lds16(Ab + (long long)(m0 + row + sr) * lda + k0 + scol, &As[buf][row * BK]);
    }
    #pragma unroll
    for (int t = 0; t < (BN * BK) / 2048; ++t) {
      const int row = w * (BN / 4) + t * RPC;
      gload_lds16(Bb + (long long)(n0 + row + sr) * ldb + k0 + scol, &Bs[buf][row * BK]);
    }
  };
  auto compute = [&](int buf) {
    #pragma unroll
    for (int kk = 0; kk < KK; ++kk) {
      const int cb = ((kk * 4 + quad) ^ xv) << 3;   // swizzled 16B slot, shorts
      short8 af[AM], bfr[AN];
      #pragma unroll
      for (int i = 0; i < AM; ++i)
        af[i] = *(const short8*)&As[buf][(wr * WTM + i * 16 + lm) * BK + cb];
      #pragma unroll
      for (int j = 0; j < AN; ++j)
        bfr[j] = *(const short8*)&Bs[buf][(wc * WTN + j * 16 + lm) * BK + cb];
      #pragma unroll
      for (int i = 0; i < AM; ++i)
        #pragma unroll
        for (int j = 0; j < AN; ++j)
          acc[i][j] = __builtin_amdgcn_mfma_f32_16x16x32_bf16(af[i], bfr[j], acc[i][j], 0, 0, 0);
    }
  };

  stage(0, 0);
  __syncthreads();               // drain preload
  int cur = 0;
  for (int k0 = BK; k0 < K; k0 += BK) {
    stage(cur ^ 1, k0);          // async prefetch into idle buffer
    compute(cur);                // MFMAs overlap the in-flight loads
    __syncthreads();             // drains prefetch; all reads of cur done
    cur ^= 1;
  }
  compute(cur);                  // last tile, no trailing barrier needed

  #pragma unroll
  for (int i = 0; i < AM; ++i) {
    #pragma unroll
    for (int j = 0; j < AN; ++j) {
      const int n = n0 + wc * WTN + j * 16 + lm;
      const float bj = BIAS ? bias[n] : 0.f;
      #pragma unroll
      for (int rr = 0; rr < 4; ++rr) {
        const int m = m0 + wr * WTM + i * 16 + quad * 4 + rr;
        float v = acc[i][j][rr] * scale + bj;
        if (RELU) v = fmaxf(v, 0.f);
        const long long co = cOff + (long long)m * ldc + n;
        if (OUTF32) ((float*)C)[co] = v;
        else        ((bf16*)C)[co] = f2b(v);
      }
    }
  }
}

// ---------------------------------------------------------------------------
// Row softmax in place over bf16 [rows][1024]; one wave per row.
// ---------------------------------------------------------------------------
__global__ __launch_bounds__(256) void softmax_kernel(bf16* __restrict__ P) {
  const int tid = threadIdx.x;
  const int lane = tid & 63;
  const int w = tid >> 6;
  const long long row = (long long)blockIdx.x * 4 + w;
  bf16* p = P + row * 1024 + lane * 16;
  float v[16];
  ld8(p, v); ld8(p + 8, v + 8);
  float m = v[0];
  #pragma unroll
  for (int t = 1; t < 16; ++t) m = fmaxf(m, v[t]);
  #pragma unroll
  for (int s = 1; s < 64; s <<= 1) m = fmaxf(m, __shfl_xor(m, s, 64));
  float sum = 0.f;
  #pragma unroll
  for (int t = 0; t < 16; ++t) { v[t] = __expf(v[t] - m); sum += v[t]; }
  #pragma unroll
  for (int s = 1; s < 64; s <<= 1) sum += __shfl_xor(sum, s, 64);
  const float inv = 1.f / sum;
  uint4 o0, o1;
  o0.x = (unsigned)bfbits(v[0]*inv)  | ((unsigned)bfbits(v[1]*inv)  << 16);
  o0.y = (unsigned)bfbits(v[2]*inv)  | ((unsigned)bfbits(v[3]*inv)  << 16);
  o0.z = (unsigned)bfbits(v[4]*inv)  | ((unsigned)bfbits(v[5]*inv)  << 16);
  o0.w = (unsigned)bfbits(v[6]*inv)  | ((unsigned)bfbits(v[7]*inv)  << 16);
  o1.x = (unsigned)bfbits(v[8]*inv)  | ((unsigned)bfbits(v[9]*inv)  << 16);
  o1.y = (unsigned)bfbits(v[10]*inv) | ((unsigned)bfbits(v[11]*inv) << 16);
  o1.z = (unsigned)bfbits(v[12]*inv) | ((unsigned)bfbits(v[13]*inv) << 16);
  o1.w = (unsigned)bfbits(v[14]*inv) | ((unsigned)bfbits(v[15]*inv) << 16);
  ((uint4*)p)[0] = o0; ((uint4*)p)[1] = o1;
}

// ---------------------------------------------------------------------------
// Per-batch: Vt_b[h][d][s] = qkv_b[s, 2048 + h*64 + d]  (64x64 LDS transpose)
// ---------------------------------------------------------------------------
__global__ __launch_bounds__(256) void transpose_v_kernel(
    const bf16* __restrict__ qkv_b, bf16* __restrict__ Vt_b) {
  __shared__ short T[64][72];
  const int tid = threadIdx.x;
  const int h = blockIdx.y;
  const int s0 = blockIdx.x * 64;
  const bf16* src = qkv_b + (long long)s0 * 3072 + 2 * ND + h * 64;
  {
    const int s = tid >> 2, c = (tid & 3) * 16;
    const uint4 a0 = *(const uint4*)(src + (long long)s * 3072 + c);
    const uint4 a1 = *(const uint4*)(src + (long long)s * 3072 + c + 8);
    *(uint4*)&T[s][c] = a0; *(uint4*)&T[s][c + 8] = a1;
  }
  __syncthreads();
  {
    const int d = tid >> 2, c = (tid & 3) * 16;
    unsigned wds[8];
    #pragma unroll
    for (int u = 0; u < 8; ++u) {
      const unsigned lo = (unsigned short)T[c + 2 * u][d];
      const unsigned hi = (unsigned short)T[c + 2 * u + 1][d];
      wds[u] = lo | (hi << 16);
    }
    bf16* dst = Vt_b + (long long)h * (NDH * NS) + (long long)d * NS + s0 + c;
    uint4 o0, o1;
    o0.x = wds[0]; o0.y = wds[1]; o0.z = wds[2]; o0.w = wds[3];
    o1.x = wds[4]; o1.y = wds[5]; o1.z = wds[6]; o1.w = wds[7];
    ((uint4*)dst)[0] = o0; ((uint4*)dst)[1] = o1;
  }
}

// ---------------------------------------------------------------------------
// Batched 1024x1024 bf16 transpose: dst[b][d][s] = src[b][s][d]
// ---------------------------------------------------------------------------
__global__ __launch_bounds__(256) void transpose_sq_kernel(
    const bf16* __restrict__ src, bf16* __restrict__ dst) {
  __shared__ short T[64][72];
  const int tid = threadIdx.x;
  const int b = blockIdx.z;
  const int s0 = blockIdx.x * 64, d0 = blockIdx.y * 64;
  const bf16* sp = src + ((long long)b * NS + s0) * ND + d0;
  {
    const int s = tid >> 2, c = (tid & 3) * 16;
    const uint4 a0 = *(const uint4*)(sp + (long long)s * ND + c);
    const uint4 a1 = *(const uint4*)(sp + (long long)s * ND + c + 8);
    *(uint4*)&T[s][c] = a0; *(uint4*)&T[s][c + 8] = a1;
  }
  __syncthreads();
  {
    const int d = tid >> 2, c = (tid & 3) * 16;
    unsigned wds[8];
    #pragma unroll
    for (int u = 0; u < 8; ++u) {
      const unsigned lo = (unsigned short)T[c + 2 * u][d];
      const unsigned hi = (unsigned short)T[c + 2 * u + 1][d];
      wds[u] = lo | (hi << 16);
    }
    bf16* dp = dst + ((long long)b * ND + d0 + d) * NS + s0 + c;
    uint4 o0, o1;
    o0.x = wds[0]; o0.y = wds[1]; o0.z = wds[2]; o0.w = wds[3];
    o1.x = wds[4]; o1.y = wds[5]; o1.z = wds[6]; o1.w = wds[7];
    ((uint4*)dp)[0] = o0; ((uint4*)dp)[1] = o1;
  }
}

// ---------------------------------------------------------------------------
// Sparse top-k selection from precomputed fp32 scores S[row][1024].
// One WAVE per row (4 rows/block); wave-local radix select.
// ---------------------------------------------------------------------------
__global__ __launch_bounds__(256) void sparse_select_kernel(
    const float* __restrict__ S, bf16* __restrict__ aw)
{
  __shared__ unsigned hist[4][256];
  const int tid = threadIdx.x;
  const int lane = tid & 63;
  const int wv = tid >> 6;
  const long long row = (long long)blockIdx.x * 4 + wv;

  float sv[16];
  const float* sp = S + row * 1024 + lane * 16;
  #pragma unroll
  for (int c = 0; c < 4; ++c) {
    const float4 v = ((const float4*)sp)[c];
    sv[4*c] = v.x; sv[4*c+1] = v.y; sv[4*c+2] = v.z; sv[4*c+3] = v.w;
  }
  unsigned key[16];
  #pragma unroll
  for (int j = 0; j < 16; ++j) {
    const unsigned u = __float_as_uint(sv[j]);
    key[j] = (u & 0x80000000u) ? ~u : (u | 0x80000000u);  // order-preserving
  }

  unsigned pref = 0u;
  int need = NTOPK;
  #pragma unroll
  for (int p = 3; p >= 0; --p) {
    *(uint4*)&hist[wv][lane * 4] = (uint4){0u, 0u, 0u, 0u};
    __syncthreads();
    const int sh = (p + 1) * 8;
    #pragma unroll
    for (int j = 0; j < 16; ++j) {
      const bool part = (p == 3) || ((key[j] >> sh) == pref);
      if (part) atomicAdd(&hist[wv][(key[j] >> (p * 8)) & 255u], 1u);
    }
    __syncthreads();
    const unsigned h0 = hist[wv][4*lane],     h1 = hist[wv][4*lane + 1];
    const unsigned h2 = hist[wv][4*lane + 2], h3 = hist[wv][4*lane + 3];
    const unsigned s3 = h3, s2 = h2 + s3, s1 = h1 + s2, s0 = h0 + s1;
    unsigned sum = s0;                      // suffix sum over lanes >= lane
    #pragma unroll
    for (int d2 = 1; d2 < 64; d2 <<= 1) {
      const unsigned t = __shfl_down(sum, d2, 64);
      if (lane < 64 - d2) sum += t;
    }
    const unsigned above = sum - s0;
    const unsigned cum[4]  = {above + s0, above + s1, above + s2, above + s3};
    const unsigned next[4] = {above + s1, above + s2, above + s3, above};
    unsigned candPref = 0u; int candNeed = 0; bool has = false;
    #pragma unroll
    for (int i = 0; i < 4; ++i) {
      if ((int)cum[i] >= need && (int)next[i] < need) {
        has = true;
        candPref = (pref << 8) | (unsigned)(4 * lane + i);
        candNeed = need - (int)next[i];
      }
    }
    const unsigned long long m = __ballot(has);
    const int srcLane = (int)(__ffsll((long long)m) - 1);
    pref = (unsigned)__shfl((int)candPref, srcLane, 64);
    need = __shfl(candNeed, srcLane, 64);
  }

  const unsigned T = pref;                  // 204th-largest key
  const unsigned tb = (T & 0x80000000u) ? (T ^ 0x80000000u) : ~T;
  const float thr = __uint_as_float(tb);

  float wvv[16];
  float psTop = 0.f, psAll = 0.f;
  #pragma unroll
  for (int j = 0; j < 16; ++j) {
    const float e = __expf(sv[j] - thr);
    psAll += e;
    const float wt = (key[j] >= T) ? e : 0.f;
    psTop += wt;
    wvv[j] = wt;
  }
  #pragma unroll
  for (int s = 1; s < 64; s <<= 1) {
    psTop += __shfl_xor(psTop, s, 64);
    psAll += __shfl_xor(psAll, s, 64);
  }
  const float inv = 1.f / (psTop + 1e-9f * psAll);

  uint4 o0, o1;
  o0.x = (unsigned)bfbits(wvv[0]*inv)  | ((unsigned)bfbits(wvv[1]*inv)  << 16);
  o0.y = (unsigned)bfbits(wvv[2]*inv)  | ((unsigned)bfbits(wvv[3]*inv)  << 16);
  o0.z = (unsigned)bfbits(wvv[4]*inv)  | ((unsigned)bfbits(wvv[5]*inv)  << 16);
  o0.w = (unsigned)bfbits(wvv[6]*inv)  | ((unsigned)bfbits(wvv[7]*inv)  << 16);
  o1.x = (unsigned)bfbits(wvv[8]*inv)  | ((unsigned)bfbits(wvv[9]*inv)  << 16);
  o1.y = (unsigned)bfbits(wvv[10]*inv) | ((unsigned)bfbits(wvv[11]*inv) << 16);
  o1.z = (unsigned)bfbits(wvv[12]*inv) | ((unsigned)bfbits(wvv[13]*inv) << 16);
  o1.w = (unsigned)bfbits(wvv[14]*inv) | ((unsigned)bfbits(wvv[15]*inv) << 16);
  bf16* op = aw + row * 1024 + lane * 16;
  ((uint4*)op)[0] = o0; ((uint4*)op)[1] = o1;
}

// ---------------------------------------------------------------------------
// fused = sig*dense + (1-sig)*sparse ; x1 = LN1(src + fused)  (bf16 out)
// ---------------------------------------------------------------------------
__global__ __launch_bounds__(256) void fuse_ln1_kernel(
    const float* __restrict__ src, const bf16* __restrict__ dense,
    const bf16* __restrict__ sparse, const float* __restrict__ lam,
    const float* __restrict__ g, const float* __restrict__ beta,
    bf16* __restrict__ x1)
{
  __shared__ float y[ND];
  __shared__ float rbuf[256];
  const int tid = threadIdx.x;
  const size_t base = (size_t)blockIdx.x * ND;
  const float sig = 1.f / (1.f + __expf(-lam[0]));
  const float c1 = 1.f - sig;
  float s1 = 0.f, s2 = 0.f;
  #pragma unroll
  for (int j = 0; j < 4; ++j) {
    const int i = tid + (j << 8);
    const float v = src[base + i] + sig * b2f(dense[base + i]) + c1 * b2f(sparse[base + i]);
    y[i] = v; s1 += v; s2 += v * v;
  }
  const float sum1 = block_sum_256(s1, rbuf, tid);
  const float sum2 = block_sum_256(s2, rbuf, tid);
  const float mean = sum1 * (1.f / ND);
  const float var  = sum2 * (1.f / ND) - mean * mean;
  const float rstd = rsqrtf(var + 1e-5f);
  #pragma unroll
  for (int j = 0; j < 4; ++j) {
    const int i = tid + (j << 8);
    x1[base + i] = f2b((y[i] - mean) * rstd * g[i] + beta[i]);
  }
}

// out = LN2(x1 + ff)  (fp32 out; ff is bf16)
__global__ __launch_bounds__(256) void ln2_kernel(
    const bf16* __restrict__ x1, const bf16* __restrict__ ff,
    const float* __restrict__ g, const float* __restrict__ beta,
    float* __restrict__ outp)
{
  __shared__ float y[ND];
  __shared__ float rbuf[256];
  const int tid = threadIdx.x;
  const size_t base = (size_t)blockIdx.x * ND;
  float s1 = 0.f, s2 = 0.f;
  #pragma unroll
  for (int j = 0; j < 4; ++j) {
    const int i = tid + (j << 8);
    const float v = b2f(x1[base + i]) + b2f(ff[base + i]);
    y[i] = v; s1 += v; s2 += v * v;
  }
  const float sum1 = block_sum_256(s1, rbuf, tid);
  const float sum2 = block_sum_256(s2, rbuf, tid);
  const float mean = sum1 * (1.f / ND);
  const float var  = sum2 * (1.f / ND) - mean * mean;
  const float rstd = rsqrtf(var + 1e-5f);
  #pragma unroll
  for (int j = 0; j < 4; ++j) {
    const int i = tid + (j << 8);
    outp[base + i] = (y[i] - mean) * rstd * g[i] + beta[i];
  }
}

// ---------------------------------------------------------------------------
extern "C" void kernel_launch(void* const* d_in, const int* in_sizes, int n_in,
                              void* d_out, int out_size, void* d_ws, size_t ws_size,
                              hipStream_t stream)
{
  const float* src        = (const float*)d_in[0];
  const float* in_proj_w  = (const float*)d_in[1];
  const float* in_proj_b  = (const float*)d_in[2];
  const float* out_proj_w = (const float*)d_in[3];
  const float* out_proj_b = (const float*)d_in[4];
  const float* Qp_w  = (const float*)d_in[5];
  const float* Qp_b  = (const float*)d_in[6];
  const float* Kp_w  = (const float*)d_in[7];
  const float* Kp_b  = (const float*)d_in[8];
  const float* Vp_w  = (const float*)d_in[9];
  const float* Vp_b  = (const float*)d_in[10];
  const float* lam   = (const float*)d_in[11];
  const float* ff1_w = (const float*)d_in[12];
  const float* ff1_b = (const float*)d_in[13];
  const float* ff2_w = (const float*)d_in[14];
  const float* ff2_b = (const float*)d_in[15];
  const float* ln1_g = (const float*)d_in[16];
  const float* ln1_b = (const float*)d_in[17];
  const float* ln2_g = (const float*)d_in[18];
  const float* ln2_b = (const float*)d_in[19];
  (void)in_sizes; (void)n_in; (void)out_size; (void)ws_size;

  // --------- workspace layout (total ~131.5 MB; 136.3 MB proven safe in R2)
  char* ws = (char*)d_ws;
  size_t off = 0;
  auto take = [&](size_t bytes) -> void* {
    void* p = ws + off; off += (bytes + 255) & ~(size_t)255; return p;
  };
  bf16*  src_bf  = (bf16*) take((size_t)NM * ND * 2);          //  8.4 MB
  bf16*  w_qkv   = (bf16*) take((size_t)3 * ND * ND * 2);      //  6.3 MB
  bf16*  w_out   = (bf16*) take((size_t)ND * ND * 2);          //  2.1 MB
  bf16*  w_vp    = (bf16*) take((size_t)ND * ND * 2);          //  2.1 MB
  bf16*  w_ff1   = (bf16*) take((size_t)NDFF * ND * 2);        //  8.4 MB
  bf16*  w_ff2   = (bf16*) take((size_t)ND * NDFF * 2);        //  8.4 MB
  bf16*  w_qk    = (bf16*) take((size_t)128 * ND * 2);         //  0.26 MB
  float* bias_qk = (float*)take(128 * 4);
  const size_t mark = off;                                     // reuse point
  bf16*  qkv     = (bf16*) take((size_t)NM * 3 * ND * 2);      // 25.2 MB [dead after attn]
  bf16*  S_b     = (bf16*) take((size_t)NH * NS * NS * 2);     // 33.5 MB [dead after attn]
  bf16*  Vt_b    = (bf16*) take((size_t)NH * NDH * NS * 2);    //  2.1 MB [dead after attn]
  bf16*  ctx     = (bf16*) take((size_t)NM * ND * 2);          //  8.4 MB [dead after step 3]
  bf16*  dense   = (bf16*) take((size_t)NM * ND * 2);          //  8.4 MB
  bf16*  QKs_bf  = (bf16*) take((size_t)NM * 128 * 2);         //  1.05 MB
  bf16*  Vsp     = (bf16*) take((size_t)NM * ND * 2);          //  8.4 MB
  bf16*  sparse  = (bf16*) take((size_t)NM * ND * 2);          //  8.4 MB
  // aliases into dead regions (qkv+S_b dead after the attention loop):
  bf16*  x1    = (bf16*)(ws + mark);                                       // [0, 8.4M)
  bf16*  h1    = (bf16*)(ws + mark + (size_t)NM * ND * 2);                 // [8.4, 42.0M)
  bf16*  ffout = (bf16*)(ws + mark + (size_t)NM * ND * 2 + (size_t)NM * NDFF * 2); // [42.0, 50.4M)
  bf16*  aw    = (bf16*)(ws + mark + 2 * (size_t)NM * ND * 2 + (size_t)NM * NDFF * 2); // [50.4, 58.8M)
  float* S_sp  = (float*)(ws + mark + (size_t)NM * ND * 2);    // [8.4, 25.2M): written 4b,
                                                               // read 6a, dead before h1
  bf16*  Vsp_t = (bf16*)ctx;  // ctx dead after step 3

  const dim3 blk(256);
  auto cast = [&](const float* in, bf16* out, int n) {
    cast_kernel<<<dim3((n + 1023) / 1024), blk, 0, stream>>>(in, out, n);
  };
  // 0. fp32 -> bf16 conversions
  cast(src,        src_bf, NM * ND);
  cast(in_proj_w,  w_qkv,  3 * ND * ND);
  cast(out_proj_w, w_out,  ND * ND);
  cast(Vp_w,       w_vp,   ND * ND);
  cast(ff1_w,      w_ff1,  NDFF * ND);
  cast(ff2_w,      w_ff2,  ND * NDFF);
  pack_qk_kernel<<<dim3(128), blk, 0, stream>>>(Qp_w, Kp_w, Qp_b, Kp_b, w_qk, bias_qk);

  // 1. qkv = src @ in_proj^T + b   [4096,3072] bf16  (768 blocks)
  mfma_gemm<128,128,32,1,0,0><<<dim3(3*ND/128, NM/128, 1), blk, 0, stream>>>(
      src_bf, w_qkv, in_proj_b, qkv, ND, ND, ND, 3*ND, 0,0, 0,0, 0,0, 1.f);

  // 2. dense MHA, per batch (S_b / Vt_b reused across b)
  for (int b = 0; b < NB; ++b) {
    const bf16* qkv_b = qkv + (size_t)b * NS * 3 * ND;
    mfma_gemm<128,128,32,0,0,0><<<dim3(NS/128, NS/128, NH), blk, 0, stream>>>(
        qkv_b, qkv_b + ND, nullptr, S_b, NDH, 3*ND, 3*ND, NS,
        0, NDH, 0, NDH, 0, (long long)NS*NS, 0.125f);
    softmax_kernel<<<dim3(NH*NS/4), blk, 0, stream>>>(S_b);
    transpose_v_kernel<<<dim3(NS/64, NH), blk, 0, stream>>>(qkv_b, Vt_b);
    // PV: 64x64 tiles, BK=64 -> 256 blocks/launch (was 128)
    mfma_gemm<64,64,64,0,0,0><<<dim3(1, NS/64, NH), blk, 0, stream>>>(
        S_b, Vt_b, nullptr, ctx + (size_t)b * NS * ND, NS, NS, NS, ND,
        0, (long long)NS*NS, 0, (long long)NDH*NS, 0, NDH, 1.f);
  }

  // 3. dense_output = ctx @ out_proj^T + b  (bf16; 128x64xBK64 -> 512 blocks)
  mfma_gemm<128,64,64,1,0,0><<<dim3(ND/64, NM/128, 1), blk, 0, stream>>>(
      ctx, w_out, out_proj_b, dense, ND, ND, ND, ND, 0,0, 0,0, 0,0, 1.f);
  // 4. QKs_bf = src @ [Qp;Kp]^T + b  (bf16 [4096][128]; 64 blocks)
  mfma_gemm<128,64,64,1,0,0><<<dim3(2, NM/128, 1), blk, 0, stream>>>(
      src_bf, w_qk, bias_qk, QKs_bf, ND, ND, ND, 128, 0,0, 0,0, 0,0, 1.f);
  // 4b. S_sp[b] = (Qs Ks^T)/8  fp32, batched over b (single K-tile at BK=64)
  mfma_gemm<128,64,64,0,0,1><<<dim3(NS/64, NS/128, NB), blk, 0, stream>>>(
      QKs_bf, QKs_bf + 64, nullptr, S_sp, 64, 128, 128, NS,
      0, (long long)NS*128, 0, (long long)NS*128, 0, (long long)NS*NS, 0.125f);
  // 5. Vsp = src @ Vp^T + b  (bf16; 512 blocks)
  mfma_gemm<128,64,64,1,0,0><<<dim3(ND/64, NM/128, 1), blk, 0, stream>>>(
      src_bf, w_vp, Vp_b, Vsp, ND, ND, ND, ND, 0,0, 0,0, 0,0, 1.f);
  // 5b. Vsp_t[b][d][s] = Vsp[b][s][d]   (ctx slot reused)
  transpose_sq_kernel<<<dim3(NS/64, ND/64, NB), blk, 0, stream>>>(Vsp, Vsp_t);
  // 6a. top-k select + normalized weights -> aw (bf16), one wave per row
  sparse_select_kernel<<<dim3(NM/4), blk, 0, stream>>>(S_sp, aw);
  // 6b. sparse = aw @ Vsp^T  (batched per b; 512 blocks)
  mfma_gemm<128,64,64,0,0,0><<<dim3(ND/64, NS/128, NB), blk, 0, stream>>>(
      aw, Vsp_t, nullptr, sparse, NS, NS, NS, ND,
      0, (long long)NS*ND, 0, (long long)ND*NS, 0, (long long)NS*ND, 1.f);
  // 7. fuse + residual + LN1 -> x1 (bf16)  [qkv/S_b dead; x1 aliases them]
  fuse_ln1_kernel<<<dim3(NM), blk, 0, stream>>>(src, dense, sparse, lam, ln1_g, ln1_b, x1);
  // 8. h1 = relu(x1 @ ff1^T + b)  (bf16; 1024 blocks)
  mfma_gemm<128,128,32,1,1,0><<<dim3(NDFF/128, NM/128, 1), blk, 0, stream>>>(
      x1, w_ff1, ff1_b, h1, ND, ND, ND, NDFF, 0,0, 0,0, 0,0, 1.f);
  // 9. ff = h1 @ ff2^T + b  (bf16; 128x64xBK64 -> 512 blocks)
  mfma_gemm<128,64,64,1,0,0><<<dim3(ND/64, NM/128, 1), blk, 0, stream>>>(
      h1, w_ff2, ff2_b, ffout, NDFF, NDFF, NDFF, ND, 0,0, 0,0, 0,0, 1.f);
  // 10. out = LN2(x1 + ff)  (fp32)
  ln2_kernel<<<dim3(NM), blk, 0, stream>>>(x1, ffout, ln2_g, ln2_b, (float*)d_out);
}

// Round 2
// 463.731 us; speedup vs baseline: 1.3744x; 1.2572x over previous
//
#include <hip/hip_runtime.h>
#include <hip/hip_bf16.h>
#include <math.h>

typedef __hip_bfloat16 bf16;
typedef __attribute__((ext_vector_type(8))) short short8;
typedef __attribute__((ext_vector_type(4))) float f32x4;

// Problem constants
#define NB 4
#define NS 1024
#define ND 1024
#define NH 16
#define NDH 64
#define NR 64
#define NDFF 4096
#define NM (NB*NS)     // 4096 rows
#define NTOPK 204      // int(1024*0.2)

static __device__ __forceinline__ float b2f(bf16 x) { return __bfloat162float(x); }
static __device__ __forceinline__ bf16  f2b(float x) { return __float2bfloat16(x); }
static __device__ __forceinline__ unsigned short bfbits(float x) {
  bf16 h = __float2bfloat16(x);
  return *reinterpret_cast<unsigned short*>(&h);
}

// async global->LDS, 16B per lane; LDS dest = wave-uniform base + lane*16
static __device__ __forceinline__ void gload_lds16(const void* g, void* l) {
  __builtin_amdgcn_global_load_lds(
      (const __attribute__((address_space(1))) void*)g,
      (__attribute__((address_space(3))) void*)l, 16, 0, 0);
}

// 8 consecutive bf16 -> fp32 (one 16B load)
static __device__ __forceinline__ void ld8(const bf16* p, float* d) {
  const uint4 u = *(const uint4*)p;
  d[0] = __uint_as_float((u.x & 0xffffu) << 16);
  d[1] = __uint_as_float(u.x & 0xffff0000u);
  d[2] = __uint_as_float((u.y & 0xffffu) << 16);
  d[3] = __uint_as_float(u.y & 0xffff0000u);
  d[4] = __uint_as_float((u.z & 0xffffu) << 16);
  d[5] = __uint_as_float(u.z & 0xffff0000u);
  d[6] = __uint_as_float((u.w & 0xffffu) << 16);
  d[7] = __uint_as_float(u.w & 0xffff0000u);
}

static __device__ __forceinline__ float block_sum_256(float v, float* rbuf, int tid) {
  rbuf[tid] = v;
  __syncthreads();
  #pragma unroll
  for (int st = 128; st > 0; st >>= 1) {
    if (tid < st) rbuf[tid] += rbuf[tid + st];
    __syncthreads();
  }
  const float r = rbuf[0];
  __syncthreads();
  return r;
}

// ---------------------------------------------------------------------------
// fp32 -> bf16 cast (n multiple of 4)
// ---------------------------------------------------------------------------
__global__ __launch_bounds__(256) void cast_kernel(const float* __restrict__ in,
                                                   bf16* __restrict__ out, int n) {
  const int i = (blockIdx.x * 256 + threadIdx.x) * 4;
  if (i < n) {
    const float4 v = *(const float4*)(in + i);
    uint2 o;
    o.x = (unsigned)bfbits(v.x) | ((unsigned)bfbits(v.y) << 16);
    o.y = (unsigned)bfbits(v.z) | ((unsigned)bfbits(v.w) << 16);
    *(uint2*)(out + i) = o;
  }
}

// Concat Qp_w/Kp_w -> bf16 [128][1024], Qp_b/Kp_b -> fp32 [128]
__global__ __launch_bounds__(256) void pack_qk_kernel(
    const float* __restrict__ Qw, const float* __restrict__ Kw,
    const float* __restrict__ Qb, const float* __restrict__ Kb,
    bf16* __restrict__ w, float* __restrict__ bias) {
  const int r = blockIdx.x;  // 0..127
  const float* srcw = (r < 64) ? (Qw + (size_t)r * ND) : (Kw + (size_t)(r - 64) * ND);
  for (int i = threadIdx.x; i < ND; i += 256) w[(size_t)r * ND + i] = f2b(srcw[i]);
  if (r == 0)
    for (int i = threadIdx.x; i < 128; i += 256)
      bias[i] = (i < 64) ? Qb[i] : Kb[i - 64];
}

// ---------------------------------------------------------------------------
// Generic batched MFMA GEMM: C = scale*(A @ W^T) (+bias), bf16 in.
// Double-buffered BK-wide software pipeline (global_load_lds width=16).
// LDS slot-XOR swizzle applied to the GLOBAL source column at stage time and
// undone at ds_read time (global_load_lds forces a linear LDS destination):
//   BK=32: slot' = slot ^ ((row>>1)&3)   BK=64: slot' = slot ^ (row&7)
// 256 threads = 4 waves in a 2x2 grid; wave tile = (BM/2)x(BN/2).
// Batch z: off = (z>>4)*Hi + (z&15)*Lo.  K multiple of BK.
// XCD-compact swizzle when gridDim.x%8==0 (perf heuristic only).
// ---------------------------------------------------------------------------
template<int BM, int BN, int BK, int BIAS, int RELU, int OUTF32>
__global__ __launch_bounds__(256) void mfma_gemm(
    const bf16* __restrict__ A, const bf16* __restrict__ W,
    const float* __restrict__ bias, void* __restrict__ C,
    int K, int lda, int ldb, int ldc,
    long long aHi, long long aLo, long long bHi, long long bLo,
    long long cHi, long long cLo, float scale)
{
  constexpr int WTM = BM / 2;
  constexpr int WTN = BN / 2;
  constexpr int AM = WTM / 16;
  constexpr int AN = WTN / 16;
  constexpr int KK = BK / 32;        // MFMA sub-steps per K-tile
  constexpr int SLOTS = BK / 8;      // 16B slots per LDS row
  constexpr int RPC = 512 / BK;      // rows per wave per gload_lds16 call
  __shared__ short As[2][BM * BK];
  __shared__ short Bs[2][BN * BK];
  const int tid  = threadIdx.x;
  const int lane = tid & 63;
  const int w    = tid >> 6;
  const int z    = blockIdx.z;
  const long long aOff = (long long)(z >> 4) * aHi + (long long)(z & 15) * aLo;
  const long long bOff = (long long)(z >> 4) * bHi + (long long)(z & 15) * bLo;
  const long long cOff = (long long)(z >> 4) * cHi + (long long)(z & 15) * cLo;

  int bx = blockIdx.x, by = blockIdx.y;
  if ((gridDim.x & 7) == 0) {
    const unsigned lin = blockIdx.y * gridDim.x + blockIdx.x;
    const unsigned Wd = gridDim.x >> 3;
    const unsigned xcd = lin & 7, i = lin >> 3;
    bx = (int)(xcd * Wd + (i % Wd));
    by = (int)(i / Wd);
  }
  const int m0 = by * BM;
  const int n0 = bx * BN;
  const int wr = w >> 1, wc = w & 1;
  const int lm = lane & 15, quad = lane >> 4;

  f32x4 acc[AM][AN];
  #pragma unroll
  for (int i = 0; i < AM; ++i)
    #pragma unroll
    for (int j = 0; j < AN; ++j) acc[i][j] = (f32x4){0.f, 0.f, 0.f, 0.f};

  // staging lane map + slot swizzle (write side, applied to GLOBAL source col)
  const int slot = lane & (SLOTS - 1);
  const int sr   = lane / SLOTS;     // row within this wave's RPC-row chunk
  const int swz  = (BK == 32) ? ((sr >> 1) & 3) : (sr & 7);
  const int scol = (slot ^ swz) << 3;  // shorts
  // read-side swizzle (row == lm mod 16; chunk bases are slot-period aligned)
  const int xv   = (BK == 32) ? ((lm >> 1) & 3) : (lm & 7);
  const bf16* Ab = A + aOff;
  const bf16* Bb = W + bOff;

  auto stage = [&](int buf, int k0) {
    #pragma unroll
    for (int t = 0; t < (BM * BK) / 2048; ++t) {
      const int row = w * (BM / 4) + t * RPC;
      gload_lds16(Ab + (long long)(m0 + row + sr) * lda + k0 + scol, &As[buf][row * BK]);
    }
    #pragma unroll
    for (int t = 0; t < (BN * BK) / 2048; ++t) {
      const int row = w * (BN / 4) + t * RPC;
      gload_lds16(Bb + (long long)(n0 + row + sr) * ldb + k0 + scol, &Bs[buf][row * BK]);
    }
  };
  auto compute = [&](int buf) {
    #pragma unroll
    for (int kk = 0; kk < KK; ++kk) {
      const int cb = ((kk * 4 + quad) ^ xv) << 3;   // swizzled 16B slot, shorts
      short8 af[AM], bfr[AN];
      #pragma unroll
      for (int i = 0; i < AM; ++i)
        af[i] = *(const short8*)&As[buf][(wr * WTM + i * 16 + lm) * BK + cb];
      #pragma unroll
      for (int j = 0; j < AN; ++j)
        bfr[j] = *(const short8*)&Bs[buf][(wc * WTN + j * 16 + lm) * BK + cb];
      #pragma unroll
      for (int i = 0; i < AM; ++i)
        #pragma unroll
        for (int j = 0; j < AN; ++j)
          acc[i][j] = __builtin_amdgcn_mfma_f32_16x16x32_bf16(af[i], bfr[j], acc[i][j], 0, 0, 0);
    }
  };

  stage(0, 0);
  __syncthreads();               // drain preload
  int cur = 0;
  for (int k0 = BK; k0 < K; k0 += BK) {
    stage(cur ^ 1, k0);          // async prefetch into idle buffer
    compute(cur);                // MFMAs overlap the in-flight loads
    __syncthreads();             // drains prefetch; all reads of cur done
    cur ^= 1;
  }
  compute(cur);                  // last tile, no trailing barrier needed

  #pragma unroll
  for (int i = 0; i < AM; ++i) {
    #pragma unroll
    for (int j = 0; j < AN; ++j) {
      const int n = n0 + wc * WTN + j * 16 + lm;
      const float bj = BIAS ? bias[n] : 0.f;
      #pragma unroll
      for (int rr = 0; rr < 4; ++rr) {
        const int m = m0 + wr * WTM + i * 16 + quad * 4 + rr;
        float v = acc[i][j][rr] * scale + bj;
        if (RELU) v = fmaxf(v, 0.f);
        const long long co = cOff + (long long)m * ldc + n;
        if (OUTF32) ((float*)C)[co] = v;
        else        ((bf16*)C)[co] = f2b(v);
      }
    }
  }
}

// ---------------------------------------------------------------------------
// Fused flash attention (dense MHA): per (q-tile of 128, b, h) block.
// Swapped QK^T: st = mfma(K_frag, Q_frag) -> S^T fragments with q = lane&15,
// kv = (lane>>4)*4+reg (+16*i). Online softmax per q-col needs only 2
// shfl_xor (over quads). P^T bf16 B-frags built in-register via shfl.
// K staged from qkv, V^T staged from Vt (precomputed transpose), both via
// global_load_lds w/ the verified XOR slot swizzle; double-buffered LDS.
// O^T accumulated in fp32; epilogue transposes through LDS for coalesced
// ctx writes. Replaces QK-GEMM + softmax + PV (eliminates S_b entirely).
// grid (NS/128, NB*NH), 256 threads.
// ---------------------------------------------------------------------------
__global__ __launch_bounds__(256) void attn_kernel(
    const bf16* __restrict__ qkv,   // [B][S][3*ND]
    const bf16* __restrict__ Vt,    // [B*H][NDH][NS]
    bf16* __restrict__ ctx)         // [B][S][ND]
{
  __shared__ short smem[2][2][64 * 64];   // [buf][K|V][4096] = 32 KB
  const int tid = threadIdx.x, lane = tid & 63, w = tid >> 6;
  const int lm = lane & 15, quad = lane >> 4;
  const int z = blockIdx.y, b = z >> 4, h = z & 15;
  const int q0 = blockIdx.x * 128;
  const bf16* Qb = qkv + (long long)b * NS * 3072 + h * 64;
  const bf16* Kb = Qb + ND;
  const bf16* Vb = Vt + (long long)z * (NDH * NS);

  // Q B-frags [j][kk]: col q = q0 + w*32 + j*16 + lm, k(d) = kk*32 + quad*8 + e
  short8 qf[2][2];
  #pragma unroll
  for (int j = 0; j < 2; ++j)
    #pragma unroll
    for (int kk = 0; kk < 2; ++kk)
      qf[j][kk] = *(const short8*)(Qb + (long long)(q0 + w * 32 + j * 16 + lm) * 3072
                                      + kk * 32 + quad * 8);

  // staging map (8 slots of 16B per 64-elem row; 8 rows per issue per wave)
  const int slot = lane & 7, sr = lane >> 3;
  const int scol = (slot ^ sr) << 3;      // shorts; involution with read side

  auto stage = [&](int buf, int t) {
    #pragma unroll
    for (int u = 0; u < 2; ++u) {
      const int row = w * 16 + u * 8;     // kv row within tile
      gload_lds16(Kb + (long long)(t * 64 + row + sr) * 3072 + scol,
                  &smem[buf][0][row * 64]);
    }
    #pragma unroll
    for (int u = 0; u < 2; ++u) {
      const int row = w * 16 + u * 8;     // d row
      gload_lds16(Vb + (long long)(row + sr) * NS + t * 64 + scol,
                  &smem[buf][1][row * 64]);
    }
  };

  f32x4 o[4][2];                          // O^T: d-tile i, q-tile j
  #pragma unroll
  for (int i = 0; i < 4; ++i)
    #pragma unroll
    for (int j = 0; j < 2; ++j) o[i][j] = (f32x4){0.f, 0.f, 0.f, 0.f};
  float m[2] = {-1e30f, -1e30f}, l[2] = {0.f, 0.f};

  stage(0, 0);
  __syncthreads();
  for (int t = 0; t < 16; ++t) {
    const int buf = t & 1;
    if (t < 15) stage(buf ^ 1, t + 1);

    // --- S^T = (K @ Q^T)/8 : st[i][j], i = kv-tile, j = q-tile
    f32x4 st[4][2];
    #pragma unroll
    for (int i = 0; i < 4; ++i)
      #pragma unroll
      for (int j = 0; j < 2; ++j) st[i][j] = (f32x4){0.f, 0.f, 0.f, 0.f};
    #pragma unroll
    for (int kk = 0; kk < 2; ++kk) {
      const int cb = ((kk * 4 + quad) ^ (lm & 7)) << 3;
      short8 ka[4];
      #pragma unroll
      for (int i = 0; i < 4; ++i)
        ka[i] = *(const short8*)&smem[buf][0][(i * 16 + lm) * 64 + cb];
      #pragma unroll
      for (int i = 0; i < 4; ++i)
        #pragma unroll
        for (int j = 0; j < 2; ++j)
          st[i][j] = __builtin_amdgcn_mfma_f32_16x16x32_bf16(ka[i], qf[j][kk], st[i][j], 0, 0, 0);
    }

    // --- online softmax per q-col (j); kv spread over 16 regs x 4 quads
    #pragma unroll
    for (int j = 0; j < 2; ++j) {
      float pm = -1e30f;
      #pragma unroll
      for (int i = 0; i < 4; ++i)
        #pragma unroll
        for (int r = 0; r < 4; ++r) {
          st[i][j][r] *= 0.125f;
          pm = fmaxf(pm, st[i][j][r]);
        }
      pm = fmaxf(pm, __shfl_xor(pm, 16, 64));
      pm = fmaxf(pm, __shfl_xor(pm, 32, 64));
      const float mn = fmaxf(m[j], pm);
      const float sc = __expf(m[j] - mn);
      float ps = 0.f;
      #pragma unroll
      for (int i = 0; i < 4; ++i)
        #pragma unroll
        for (int r = 0; r < 4; ++r) {
          const float e = __expf(st[i][j][r] - mn);
          st[i][j][r] = e;                 // st now holds P^T
          ps += e;
        }
      ps += __shfl_xor(ps, 16, 64);
      ps += __shfl_xor(ps, 32, 64);
      l[j] = l[j] * sc + ps;
      m[j] = mn;
      #pragma unroll
      for (int i = 0; i < 4; ++i)
        #pragma unroll
        for (int r = 0; r < 4; ++r) o[i][j][r] *= sc;
    }

    // --- pack P^T to bf16 pairs: u0 = (r0,r1), u1 = (r2,r3)
    unsigned u0[4][2], u1[4][2];
    #pragma unroll
    for (int i = 0; i < 4; ++i)
      #pragma unroll
      for (int j = 0; j < 2; ++j) {
        u0[i][j] = (unsigned)bfbits(st[i][j][0]) | ((unsigned)bfbits(st[i][j][1]) << 16);
        u1[i][j] = (unsigned)bfbits(st[i][j][2]) | ((unsigned)bfbits(st[i][j][3]) << 16);
      }
    // target frag (kk,j) elem e: kv = kk*32+quad*8+e comes from
    //   i_src = kk*2 + (quad>>1), src lane = ((quad&1)*2 + (e>>2))*16 + lm, r = e&3
    const int s0l = ((quad & 1) * 2) * 16 + lm;
    const int s1l = s0l + 16;
    const bool hi = (quad >> 1) != 0;

    // --- O^T += V^T @ P^T
    #pragma unroll
    for (int kk = 0; kk < 2; ++kk) {
      short8 pf[2];
      #pragma unroll
      for (int j = 0; j < 2; ++j) {
        const unsigned a0 = __shfl(u0[kk * 2][j],     s0l, 64);
        const unsigned a1 = __shfl(u1[kk * 2][j],     s0l, 64);
        const unsigned b0 = __shfl(u0[kk * 2 + 1][j], s0l, 64);
        const unsigned b1 = __shfl(u1[kk * 2 + 1][j], s0l, 64);
        const unsigned c0 = __shfl(u0[kk * 2][j],     s1l, 64);
        const unsigned c1 = __shfl(u1[kk * 2][j],     s1l, 64);
        const unsigned d0 = __shfl(u0[kk * 2 + 1][j], s1l, 64);
        const unsigned d1 = __shfl(u1[kk * 2 + 1][j], s1l, 64);
        union { uint4 u; short8 s; } cv;
        cv.u.x = hi ? b0 : a0; cv.u.y = hi ? b1 : a1;
        cv.u.z = hi ? d0 : c0; cv.u.w = hi ? d1 : c1;
        pf[j] = cv.s;
      }
      const int cb = ((kk * 4 + quad) ^ (lm & 7)) << 3;
      short8 va[4];
      #pragma unroll
      for (int i = 0; i < 4; ++i)
        va[i] = *(const short8*)&smem[buf][1][(i * 16 + lm) * 64 + cb];
      #pragma unroll
      for (int i = 0; i < 4; ++i)
        #pragma unroll
        for (int j = 0; j < 2; ++j)
          o[i][j] = __builtin_amdgcn_mfma_f32_16x16x32_bf16(va[i], pf[j], o[i][j], 0, 0, 0);
    }
    __syncthreads();   // drains prefetch; all reads of buf done
  }

  // --- epilogue: normalize, transpose O^T -> O through LDS, coalesced store
  short (*OL)[72] = (short(*)[72])&smem[0][0][0];   // 128 x 72 = 18.4 KB
  #pragma unroll
  for (int j = 0; j < 2; ++j) {
    const float inv = 1.f / l[j];
    #pragma unroll
    for (int i = 0; i < 4; ++i) {
      uint2 u;
      u.x = (unsigned)bfbits(o[i][j][0] * inv) | ((unsigned)bfbits(o[i][j][1] * inv) << 16);
      u.y = (unsigned)bfbits(o[i][j][2] * inv) | ((unsigned)bfbits(o[i][j][3] * inv) << 16);
      *(uint2*)&OL[w * 32 + j * 16 + lm][i * 16 + quad * 4] = u;
    }
  }
  __syncthreads();
  {
    const int q = tid >> 1, c = (tid & 1) * 32;
    const uint4 r0 = *(const uint4*)&OL[q][c];
    const uint4 r1 = *(const uint4*)&OL[q][c + 8];
    const uint4 r2 = *(const uint4*)&OL[q][c + 16];
    const uint4 r3 = *(const uint4*)&OL[q][c + 24];
    bf16* dst = ctx + ((long long)(b * NS + q0 + q)) * 1024 + h * 64 + c;
    ((uint4*)dst)[0] = r0; ((uint4*)dst)[1] = r1;
    ((uint4*)dst)[2] = r2; ((uint4*)dst)[3] = r3;
  }
}

// ---------------------------------------------------------------------------
// All-batch: Vt[b*16+h][d][s] = qkv[b][s][2048 + h*64 + d]  (64x64 transpose)
// ---------------------------------------------------------------------------
__global__ __launch_bounds__(256) void transpose_v_kernel(
    const bf16* __restrict__ qkv, bf16* __restrict__ Vt) {
  __shared__ short T[64][72];
  const int tid = threadIdx.x;
  const int h = blockIdx.y;
  const int b = blockIdx.z;
  const int s0 = blockIdx.x * 64;
  const bf16* src = qkv + ((long long)b * NS + s0) * 3072 + 2 * ND + h * 64;
  {
    const int s = tid >> 2, c = (tid & 3) * 16;
    const uint4 a0 = *(const uint4*)(src + (long long)s * 3072 + c);
    const uint4 a1 = *(const uint4*)(src + (long long)s * 3072 + c + 8);
    *(uint4*)&T[s][c] = a0; *(uint4*)&T[s][c + 8] = a1;
  }
  __syncthreads();
  {
    const int d = tid >> 2, c = (tid & 3) * 16;
    unsigned wds[8];
    #pragma unroll
    for (int u = 0; u < 8; ++u) {
      const unsigned lo = (unsigned short)T[c + 2 * u][d];
      const unsigned hi = (unsigned short)T[c + 2 * u + 1][d];
      wds[u] = lo | (hi << 16);
    }
    bf16* dst = Vt + (long long)(b * NH + h) * (NDH * NS) + (long long)d * NS + s0 + c;
    uint4 o0, o1;
    o0.x = wds[0]; o0.y = wds[1]; o0.z = wds[2]; o0.w = wds[3];
    o1.x = wds[4]; o1.y = wds[5]; o1.z = wds[6]; o1.w = wds[7];
    ((uint4*)dst)[0] = o0; ((uint4*)dst)[1] = o1;
  }
}

// ---------------------------------------------------------------------------
// Batched 1024x1024 bf16 transpose: dst[b][d][s] = src[b][s][d]
// ---------------------------------------------------------------------------
__global__ __launch_bounds__(256) void transpose_sq_kernel(
    const bf16* __restrict__ src, bf16* __restrict__ dst) {
  __shared__ short T[64][72];
  const int tid = threadIdx.x;
  const int b = blockIdx.z;
  const int s0 = blockIdx.x * 64, d0 = blockIdx.y * 64;
  const bf16* sp = src + ((long long)b * NS + s0) * ND + d0;
  {
    const int s = tid >> 2, c = (tid & 3) * 16;
    const uint4 a0 = *(const uint4*)(sp + (long long)s * ND + c);
    const uint4 a1 = *(const uint4*)(sp + (long long)s * ND + c + 8);
    *(uint4*)&T[s][c] = a0; *(uint4*)&T[s][c + 8] = a1;
  }
  __syncthreads();
  {
    const int d = tid >> 2, c = (tid & 3) * 16;
    unsigned wds[8];
    #pragma unroll
    for (int u = 0; u < 8; ++u) {
      const unsigned lo = (unsigned short)T[c + 2 * u][d];
      const unsigned hi = (unsigned short)T[c + 2 * u + 1][d];
      wds[u] = lo | (hi << 16);
    }
    bf16* dp = dst + ((long long)b * ND + d0 + d) * NS + s0 + c;
    uint4 o0, o1;
    o0.x = wds[0]; o0.y = wds[1]; o0.z = wds[2]; o0.w = wds[3];
    o1.x = wds[4]; o1.y = wds[5]; o1.z = wds[6]; o1.w = wds[7];
    ((uint4*)dp)[0] = o0; ((uint4*)dp)[1] = o1;
  }
}

// ---------------------------------------------------------------------------
// Sparse top-k selection from precomputed fp32 scores S[row][1024].
// One WAVE per row (4 rows/block); wave-local radix select.
// ---------------------------------------------------------------------------
__global__ __launch_bounds__(256) void sparse_select_kernel(
    const float* __restrict__ S, bf16* __restrict__ aw)
{
  __shared__ unsigned hist[4][256];
  const int tid = threadIdx.x;
  const int lane = tid & 63;
  const int wv = tid >> 6;
  const long long row = (long long)blockIdx.x * 4 + wv;

  float sv[16];
  const float* sp = S + row * 1024 + lane * 16;
  #pragma unroll
  for (int c = 0; c < 4; ++c) {
    const float4 v = ((const float4*)sp)[c];
    sv[4*c] = v.x; sv[4*c+1] = v.y; sv[4*c+2] = v.z; sv[4*c+3] = v.w;
  }
  unsigned key[16];
  #pragma unroll
  for (int j = 0; j < 16; ++j) {
    const unsigned u = __float_as_uint(sv[j]);
    key[j] = (u & 0x80000000u) ? ~u : (u | 0x80000000u);  // order-preserving
  }

  unsigned pref = 0u;
  int need = NTOPK;
  #pragma unroll
  for (int p = 3; p >= 0; --p) {
    *(uint4*)&hist[wv][lane * 4] = (uint4){0u, 0u, 0u, 0u};
    __syncthreads();
    const int sh = (p + 1) * 8;
    #pragma unroll
    for (int j = 0; j < 16; ++j) {
      const bool part = (p == 3) || ((key[j] >> sh) == pref);
      if (part) atomicAdd(&hist[wv][(key[j] >> (p * 8)) & 255u], 1u);
    }
    __syncthreads();
    const unsigned h0 = hist[wv][4*lane],     h1 = hist[wv][4*lane + 1];
    const unsigned h2 = hist[wv][4*lane + 2], h3 = hist[wv][4*lane + 3];
    const unsigned s3 = h3, s2 = h2 + s3, s1 = h1 + s2, s0 = h0 + s1;
    unsigned sum = s0;                      // suffix sum over lanes >= lane
    #pragma unroll
    for (int d2 = 1; d2 < 64; d2 <<= 1) {
      const unsigned t = __shfl_down(sum, d2, 64);
      if (lane < 64 - d2) sum += t;
    }
    const unsigned above = sum - s0;
    const unsigned cum[4]  = {above + s0, above + s1, above + s2, above + s3};
    const unsigned next[4] = {above + s1, above + s2, above + s3, above};
    unsigned candPref = 0u; int candNeed = 0; bool has = false;
    #pragma unroll
    for (int i = 0; i < 4; ++i) {
      if ((int)cum[i] >= need && (int)next[i] < need) {
        has = true;
        candPref = (pref << 8) | (unsigned)(4 * lane + i);
        candNeed = need - (int)next[i];
      }
    }
    const unsigned long long m = __ballot(has);
    const int srcLane = (int)(__ffsll((long long)m) - 1);
    pref = (unsigned)__shfl((int)candPref, srcLane, 64);
    need = __shfl(candNeed, srcLane, 64);
  }

  const unsigned T = pref;                  // 204th-largest key
  const unsigned tb = (T & 0x80000000u) ? (T ^ 0x80000000u) : ~T;
  const float thr = __uint_as_float(tb);

  float wvv[16];
  float psTop = 0.f, psAll = 0.f;
  #pragma unroll
  for (int j = 0; j < 16; ++j) {
    const float e = __expf(sv[j] - thr);
    psAll += e;
    const float wt = (key[j] >= T) ? e : 0.f;
    psTop += wt;
    wvv[j] = wt;
  }
  #pragma unroll
  for (int s = 1; s < 64; s <<= 1) {
    psTop += __shfl_xor(psTop, s, 64);
    psAll += __shfl_xor(psAll, s, 64);
  }
  const float inv = 1.f / (psTop + 1e-9f * psAll);

  uint4 o0, o1;
  o0.x = (unsigned)bfbits(wvv[0]*inv)  | ((unsigned)bfbits(wvv[1]*inv)  << 16);
  o0.y = (unsigned)bfbits(wvv[2]*inv)  | ((unsigned)bfbits(wvv[3]*inv)  << 16);
  o0.z = (unsigned)bfbits(wvv[4]*inv)  | ((unsigned)bfbits(wvv[5]*inv)  << 16);
  o0.w = (unsigned)bfbits(wvv[6]*inv)  | ((unsigned)bfbits(wvv[7]*inv)  << 16);
  o1.x = (unsigned)bfbits(wvv[8]*inv)  | ((unsigned)bfbits(wvv[9]*inv)  << 16);
  o1.y = (unsigned)bfbits(wvv[10]*inv) | ((unsigned)bfbits(wvv[11]*inv) << 16);
  o1.z = (unsigned)bfbits(wvv[12]*inv) | ((unsigned)bfbits(wvv[13]*inv) << 16);
  o1.w = (unsigned)bfbits(wvv[14]*inv) | ((unsigned)bfbits(wvv[15]*inv) << 16);
  bf16* op = aw + row * 1024 + lane * 16;
  ((uint4*)op)[0] = o0; ((uint4*)op)[1] = o1;
}

// ---------------------------------------------------------------------------
// fused = sig*dense + (1-sig)*sparse ; x1 = LN1(src + fused)  (bf16 out)
// ---------------------------------------------------------------------------
__global__ __launch_bounds__(256) void fuse_ln1_kernel(
    const float* __restrict__ src, const bf16* __restrict__ dense,
    const bf16* __restrict__ sparse, const float* __restrict__ lam,
    const float* __restrict__ g, const float* __restrict__ beta,
    bf16* __restrict__ x1)
{
  __shared__ float y[ND];
  __shared__ float rbuf[256];
  const int tid = threadIdx.x;
  const size_t base = (size_t)blockIdx.x * ND;
  const float sig = 1.f / (1.f + __expf(-lam[0]));
  const float c1 = 1.f - sig;
  float s1 = 0.f, s2 = 0.f;
  #pragma unroll
  for (int j = 0; j < 4; ++j) {
    const int i = tid + (j << 8);
    const float v = src[base + i] + sig * b2f(dense[base + i]) + c1 * b2f(sparse[base + i]);
    y[i] = v; s1 += v; s2 += v * v;
  }
  const float sum1 = block_sum_256(s1, rbuf, tid);
  const float sum2 = block_sum_256(s2, rbuf, tid);
  const float mean = sum1 * (1.f / ND);
  const float var  = sum2 * (1.f / ND) - mean * mean;
  const float rstd = rsqrtf(var + 1e-5f);
  #pragma unroll
  for (int j = 0; j < 4; ++j) {
    const int i = tid + (j << 8);
    x1[base + i] = f2b((y[i] - mean) * rstd * g[i] + beta[i]);
  }
}

// out = LN2(x1 + ff)  (fp32 out; ff is bf16)
__global__ __launch_bounds__(256) void ln2_kernel(
    const bf16* __restrict__ x1, const bf16* __restrict__ ff,
    const float* __restrict__ g, const float* __restrict__ beta,
    float* __restrict__ outp)
{
  __shared__ float y[ND];
  __shared__ float rbuf[256];
  const int tid = threadIdx.x;
  const size_t base = (size_t)blockIdx.x * ND;
  float s1 = 0.f, s2 = 0.f;
  #pragma unroll
  for (int j = 0; j < 4; ++j) {
    const int i = tid + (j << 8);
    const float v = b2f(x1[base + i]) + b2f(ff[base + i]);
    y[i] = v; s1 += v; s2 += v * v;
  }
  const float sum1 = block_sum_256(s1, rbuf, tid);
  const float sum2 = block_sum_256(s2, rbuf, tid);
  const float mean = sum1 * (1.f / ND);
  const float var  = sum2 * (1.f / ND) - mean * mean;
  const float rstd = rsqrtf(var + 1e-5f);
  #pragma unroll
  for (int j = 0; j < 4; ++j) {
    const int i = tid + (j << 8);
    outp[base + i] = (y[i] - mean) * rstd * g[i] + beta[i];
  }
}

// ---------------------------------------------------------------------------
extern "C" void kernel_launch(void* const* d_in, const int* in_sizes, int n_in,
                              void* d_out, int out_size, void* d_ws, size_t ws_size,
                              hipStream_t stream)
{
  const float* src        = (const float*)d_in[0];
  const float* in_proj_w  = (const float*)d_in[1];
  const float* in_proj_b  = (const float*)d_in[2];
  const float* out_proj_w = (const float*)d_in[3];
  const float* out_proj_b = (const float*)d_in[4];
  const float* Qp_w  = (const float*)d_in[5];
  const float* Qp_b  = (const float*)d_in[6];
  const float* Kp_w  = (const float*)d_in[7];
  const float* Kp_b  = (const float*)d_in[8];
  const float* Vp_w  = (const float*)d_in[9];
  const float* Vp_b  = (const float*)d_in[10];
  const float* lam   = (const float*)d_in[11];
  const float* ff1_w = (const float*)d_in[12];
  const float* ff1_b = (const float*)d_in[13];
  const float* ff2_w = (const float*)d_in[14];
  const float* ff2_b = (const float*)d_in[15];
  const float* ln1_g = (const float*)d_in[16];
  const float* ln1_b = (const float*)d_in[17];
  const float* ln2_g = (const float*)d_in[18];
  const float* ln2_b = (const float*)d_in[19];
  (void)in_sizes; (void)n_in; (void)out_size; (void)ws_size;

  // --------- workspace layout (offsets IDENTICAL to the proven layout;
  // S_b's 33.5 MB slot now holds the all-batch Vt (8.4 MB needed))
  char* ws = (char*)d_ws;
  size_t off = 0;
  auto take = [&](size_t bytes) -> void* {
    void* p = ws + off; off += (bytes + 255) & ~(size_t)255; return p;
  };
  bf16*  src_bf  = (bf16*) take((size_t)NM * ND * 2);          //  8.4 MB
  bf16*  w_qkv   = (bf16*) take((size_t)3 * ND * ND * 2);      //  6.3 MB
  bf16*  w_out   = (bf16*) take((size_t)ND * ND * 2);          //  2.1 MB
  bf16*  w_vp    = (bf16*) take((size_t)ND * ND * 2);          //  2.1 MB
  bf16*  w_ff1   = (bf16*) take((size_t)NDFF * ND * 2);        //  8.4 MB
  bf16*  w_ff2   = (bf16*) take((size_t)ND * NDFF * 2);        //  8.4 MB
  bf16*  w_qk    = (bf16*) take((size_t)128 * ND * 2);         //  0.26 MB
  float* bias_qk = (float*)take(128 * 4);
  const size_t mark = off;                                     // reuse point
  bf16*  qkv     = (bf16*) take((size_t)NM * 3 * ND * 2);      // 25.2 MB [dead after attn]
  bf16*  Vt_all  = (bf16*) take((size_t)NH * NS * NS * 2);     // slot 33.5 MB (uses 8.4) [dead after attn]
  bf16*  Vt_old  = (bf16*) take((size_t)NH * NDH * NS * 2);    //  2.1 MB [unused slot, keeps offsets]
  bf16*  ctx     = (bf16*) take((size_t)NM * ND * 2);          //  8.4 MB [dead after step 3]
  bf16*  dense   = (bf16*) take((size_t)NM * ND * 2);          //  8.4 MB
  bf16*  QKs_bf  = (bf16*) take((size_t)NM * 128 * 2);         //  1.05 MB
  bf16*  Vsp     = (bf16*) take((size_t)NM * ND * 2);          //  8.4 MB
  bf16*  sparse  = (bf16*) take((size_t)NM * ND * 2);          //  8.4 MB
  (void)Vt_old;
  // aliases into dead regions (qkv+Vt_all dead after the attention):
  bf16*  x1    = (bf16*)(ws + mark);                                       // [0, 8.4M)
  bf16*  h1    = (bf16*)(ws + mark + (size_t)NM * ND * 2);                 // [8.4, 42.0M)
  bf16*  ffout = (bf16*)(ws + mark + (size_t)NM * ND * 2 + (size_t)NM * NDFF * 2); // [42.0, 50.4M)
  bf16*  aw    = (bf16*)(ws + mark + 2 * (size_t)NM * ND * 2 + (size_t)NM * NDFF * 2); // [50.4, 58.8M)
  float* S_sp  = (float*)(ws + mark + (size_t)NM * ND * 2);    // [8.4, 25.2M): written 4b,
                                                               // read 6a, dead before h1
  bf16*  Vsp_t = (bf16*)ctx;  // ctx dead after step 3

  const dim3 blk(256);
  auto cast = [&](const float* in, bf16* out, int n) {
    cast_kernel<<<dim3((n + 1023) / 1024), blk, 0, stream>>>(in, out, n);
  };
  // 0. fp32 -> bf16 conversions
  cast(src,        src_bf, NM * ND);
  cast(in_proj_w,  w_qkv,  3 * ND * ND);
  cast(out_proj_w, w_out,  ND * ND);
  cast(Vp_w,       w_vp,   ND * ND);
  cast(ff1_w,      w_ff1,  NDFF * ND);
  cast(ff2_w,      w_ff2,  ND * NDFF);
  pack_qk_kernel<<<dim3(128), blk, 0, stream>>>(Qp_w, Kp_w, Qp_b, Kp_b, w_qk, bias_qk);

  // 1. qkv = src @ in_proj^T + b   [4096,3072] bf16  (768 blocks)
  mfma_gemm<128,128,32,1,0,0><<<dim3(3*ND/128, NM/128, 1), blk, 0, stream>>>(
      src_bf, w_qkv, in_proj_b, qkv, ND, ND, ND, 3*ND, 0,0, 0,0, 0,0, 1.f);

  // 2. dense MHA: V transpose (all batches) + fused flash attention
  transpose_v_kernel<<<dim3(NS/64, NH, NB), blk, 0, stream>>>(qkv, Vt_all);
  attn_kernel<<<dim3(NS/128, NB*NH), blk, 0, stream>>>(qkv, Vt_all, ctx);

  // 3. dense_output = ctx @ out_proj^T + b  (bf16; 128x64xBK64 -> 512 blocks)
  mfma_gemm<128,64,64,1,0,0><<<dim3(ND/64, NM/128, 1), blk, 0, stream>>>(
      ctx, w_out, out_proj_b, dense, ND, ND, ND, ND, 0,0, 0,0, 0,0, 1.f);
  // 4. QKs_bf = src @ [Qp;Kp]^T + b  (bf16 [4096][128]; 64 blocks)
  mfma_gemm<128,64,64,1,0,0><<<dim3(2, NM/128, 1), blk, 0, stream>>>(
      src_bf, w_qk, bias_qk, QKs_bf, ND, ND, ND, 128, 0,0, 0,0, 0,0, 1.f);
  // 4b. S_sp[b] = (Qs Ks^T)/8  fp32, batched over b (single K-tile at BK=64)
  mfma_gemm<128,64,64,0,0,1><<<dim3(NS/64, NS/128, NB), blk, 0, stream>>>(
      QKs_bf, QKs_bf + 64, nullptr, S_sp, 64, 128, 128, NS,
      0, (long long)NS*128, 0, (long long)NS*128, 0, (long long)NS*NS, 0.125f);
  // 5. Vsp = src @ Vp^T + b  (bf16; 512 blocks)
  mfma_gemm<128,64,64,1,0,0><<<dim3(ND/64, NM/128, 1), blk, 0, stream>>>(
      src_bf, w_vp, Vp_b, Vsp, ND, ND, ND, ND, 0,0, 0,0, 0,0, 1.f);
  // 5b. Vsp_t[b][d][s] = Vsp[b][s][d]   (ctx slot reused)
  transpose_sq_kernel<<<dim3(NS/64, ND/64, NB), blk, 0, stream>>>(Vsp, Vsp_t);
  // 6a. top-k select + normalized weights -> aw (bf16), one wave per row
  sparse_select_kernel<<<dim3(NM/4), blk, 0, stream>>>(S_sp, aw);
  // 6b. sparse = aw @ Vsp^T  (batched per b; 512 blocks)
  mfma_gemm<128,64,64,0,0,0><<<dim3(ND/64, NS/128, NB), blk, 0, stream>>>(
      aw, Vsp_t, nullptr, sparse, NS, NS, NS, ND,
      0, (long long)NS*ND, 0, (long long)ND*NS, 0, (long long)NS*ND, 1.f);
  // 7. fuse + residual + LN1 -> x1 (bf16)  [qkv/Vt_all dead; x1 aliases them]
  fuse_ln1_kernel<<<dim3(NM), blk, 0, stream>>>(src, dense, sparse, lam, ln1_g, ln1_b, x1);
  // 8. h1 = relu(x1 @ ff1^T + b)  (bf16; 1024 blocks)
  mfma_gemm<128,128,32,1,1,0><<<dim3(NDFF/128, NM/128, 1), blk, 0, stream>>>(
      x1, w_ff1, ff1_b, h1, ND, ND, ND, NDFF, 0,0, 0,0, 0,0, 1.f);
  // 9. ff = h1 @ ff2^T + b  (bf16; 128x64xBK64 -> 512 blocks)
  mfma_gemm<128,64,64,1,0,0><<<dim3(ND/64, NM/128, 1), blk, 0, stream>>>(
      h1, w_ff2, ff2_b, ffout, NDFF, NDFF, NDFF, ND, 0,0, 0,0, 0,0, 1.f);
  // 10. out = LN2(x1 + ff)  (fp32)
  ln2_kernel<<<dim3(NM), blk, 0, stream>>>(x1, ffout, ln2_g, ln2_b, (float*)d_out);
}

// Round 3
// 445.897 us; speedup vs baseline: 1.4293x; 1.0400x over previous
//
#include <hip/hip_runtime.h>
#include <hip/hip_bf16.h>
#include <math.h>

typedef __hip_bfloat16 bf16;
typedef __attribute__((ext_vector_type(8))) short short8;
typedef __attribute__((ext_vector_type(4))) float f32x4;

// Problem constants
#define NB 4
#define NS 1024
#define ND 1024
#define NH 16
#define NDH 64
#define NR 64
#define NDFF 4096
#define NM (NB*NS)     // 4096 rows
#define NTOPK 204      // int(1024*0.2)

static __device__ __forceinline__ float b2f(bf16 x) { return __bfloat162float(x); }
static __device__ __forceinline__ bf16  f2b(float x) { return __float2bfloat16(x); }
static __device__ __forceinline__ unsigned short bfbits(float x) {
  bf16 h = __float2bfloat16(x);
  return *reinterpret_cast<unsigned short*>(&h);
}

// async global->LDS, 16B per lane; LDS dest = wave-uniform base + lane*16
static __device__ __forceinline__ void gload_lds16(const void* g, void* l) {
  __builtin_amdgcn_global_load_lds(
      (const __attribute__((address_space(1))) void*)g,
      (__attribute__((address_space(3))) void*)l, 16, 0, 0);
}

// counted vmcnt wait (T4): wait own outstanding VMEM ops <= N, leaving the
// newest N (the in-flight prefetch) pending across the following barrier.
template<int N> static __device__ __forceinline__ void vm_wait() {
  if constexpr (N == 0)       asm volatile("s_waitcnt vmcnt(0)" ::: "memory");
  else if constexpr (N == 2)  asm volatile("s_waitcnt vmcnt(2)" ::: "memory");
  else if constexpr (N == 4)  asm volatile("s_waitcnt vmcnt(4)" ::: "memory");
  else if constexpr (N == 6)  asm volatile("s_waitcnt vmcnt(6)" ::: "memory");
  else if constexpr (N == 8)  asm volatile("s_waitcnt vmcnt(8)" ::: "memory");
  else if constexpr (N == 12) asm volatile("s_waitcnt vmcnt(12)" ::: "memory");
  else static_assert(N == 0, "unsupported vmcnt");
}
// raw barrier (no implicit vmcnt drain); memory clobber = compiler fence so
// LDS accesses cannot be moved across it.
static __device__ __forceinline__ void bar() {
  asm volatile("s_barrier" ::: "memory");
}

// 8 consecutive bf16 -> fp32 (one 16B load)
static __device__ __forceinline__ void ld8(const bf16* p, float* d) {
  const uint4 u = *(const uint4*)p;
  d[0] = __uint_as_float((u.x & 0xffffu) << 16);
  d[1] = __uint_as_float(u.x & 0xffff0000u);
  d[2] = __uint_as_float((u.y & 0xffffu) << 16);
  d[3] = __uint_as_float(u.y & 0xffff0000u);
  d[4] = __uint_as_float((u.z & 0xffffu) << 16);
  d[5] = __uint_as_float(u.z & 0xffff0000u);
  d[6] = __uint_as_float((u.w & 0xffffu) << 16);
  d[7] = __uint_as_float(u.w & 0xffff0000u);
}

static __device__ __forceinline__ float block_sum_256(float v, float* rbuf, int tid) {
  rbuf[tid] = v;
  __syncthreads();
  #pragma unroll
  for (int st = 128; st > 0; st >>= 1) {
    if (tid < st) rbuf[tid] += rbuf[tid + st];
    __syncthreads();
  }
  const float r = rbuf[0];
  __syncthreads();
  return r;
}

// ---------------------------------------------------------------------------
// Fused fp32 -> bf16 cast over 6 regions (each a multiple of 1024 elems).
// One launch replaces 6; region lookup is block-uniform.
// ---------------------------------------------------------------------------
struct CastArgs {
  const float* in[6];
  bf16* out[6];
  unsigned end[6];   // cumulative block counts
};
__global__ __launch_bounds__(256) void cast6_kernel(CastArgs a) {
  const unsigned b = blockIdx.x;
  int r = 0; unsigned base = 0;
  #pragma unroll
  for (int k = 0; k < 5; ++k)
    if (b >= a.end[k]) { r = k + 1; base = a.end[k]; }
  const float* in = a.in[r];
  bf16* out = a.out[r];
  const unsigned i = ((b - base) * 256 + threadIdx.x) * 4;
  const float4 v = *(const float4*)(in + i);
  uint2 o;
  o.x = (unsigned)bfbits(v.x) | ((unsigned)bfbits(v.y) << 16);
  o.y = (unsigned)bfbits(v.z) | ((unsigned)bfbits(v.w) << 16);
  *(uint2*)(out + i) = o;
}

// Concat Qp_w/Kp_w -> bf16 [128][1024], Qp_b/Kp_b -> fp32 [128]
__global__ __launch_bounds__(256) void pack_qk_kernel(
    const float* __restrict__ Qw, const float* __restrict__ Kw,
    const float* __restrict__ Qb, const float* __restrict__ Kb,
    bf16* __restrict__ w, float* __restrict__ bias) {
  const int r = blockIdx.x;  // 0..127
  const float* srcw = (r < 64) ? (Qw + (size_t)r * ND) : (Kw + (size_t)(r - 64) * ND);
  for (int i = threadIdx.x; i < ND; i += 256) w[(size_t)r * ND + i] = f2b(srcw[i]);
  if (r == 0)
    for (int i = threadIdx.x; i < 128; i += 256)
      bias[i] = (i < 64) ? Qb[i] : Kb[i - 64];
}

// ---------------------------------------------------------------------------
// Generic batched MFMA GEMM: C = scale*(A @ W^T) (+bias), bf16 in.
// Double-buffered BK-wide pipeline with COUNTED vmcnt (T4): per K-iter
//   stage(next buf) ; s_waitcnt vmcnt(L) ; s_barrier ; compute(cur) ; s_barrier
// The wait covers only the PREVIOUS iteration's loads (latency hidden under
// the previous compute); the fresh prefetch stays in flight across both
// barriers (never vmcnt(0) in the main loop). Wait-before-barrier makes each
// wave's loads visible to all at barrier-exit; the trailing barrier protects
// the buffer overwrite on the next iteration.
// LDS slot-XOR swizzle applied to the GLOBAL source column at stage time and
// undone at ds_read time (global_load_lds forces a linear LDS destination):
//   BK=32: slot' = slot ^ ((row>>1)&3)   BK=64: slot' = slot ^ (row&7)
// 256 threads = 4 waves in a 2x2 grid; wave tile = (BM/2)x(BN/2).
// Batch z: off = (z>>4)*Hi + (z&15)*Lo.  K multiple of BK.
// XCD-compact swizzle when gridDim.x%8==0 (perf heuristic only).
// ---------------------------------------------------------------------------
template<int BM, int BN, int BK, int BIAS, int RELU, int OUTF32>
__global__ __launch_bounds__(256) void mfma_gemm(
    const bf16* __restrict__ A, const bf16* __restrict__ W,
    const float* __restrict__ bias, void* __restrict__ C,
    int K, int lda, int ldb, int ldc,
    long long aHi, long long aLo, long long bHi, long long bLo,
    long long cHi, long long cLo, float scale)
{
  constexpr int WTM = BM / 2;
  constexpr int WTN = BN / 2;
  constexpr int AM = WTM / 16;
  constexpr int AN = WTN / 16;
  constexpr int KK = BK / 32;        // MFMA sub-steps per K-tile
  constexpr int SLOTS = BK / 8;      // 16B slots per LDS row
  constexpr int RPC = 512 / BK;      // rows per wave per gload_lds16 call
  constexpr int LPW = (BM * BK) / 2048 + (BN * BK) / 2048;  // loads/wave/stage
  __shared__ short As[2][BM * BK];
  __shared__ short Bs[2][BN * BK];
  const int tid  = threadIdx.x;
  const int lane = tid & 63;
  const int w    = tid >> 6;
  const int z    = blockIdx.z;
  const long long aOff = (long long)(z >> 4) * aHi + (long long)(z & 15) * aLo;
  const long long bOff = (long long)(z >> 4) * bHi + (long long)(z & 15) * bLo;
  const long long cOff = (long long)(z >> 4) * cHi + (long long)(z & 15) * cLo;

  int bx = blockIdx.x, by = blockIdx.y;
  if ((gridDim.x & 7) == 0) {
    const unsigned lin = blockIdx.y * gridDim.x + blockIdx.x;
    const unsigned Wd = gridDim.x >> 3;
    const unsigned xcd = lin & 7, i = lin >> 3;
    bx = (int)(xcd * Wd + (i % Wd));
    by = (int)(i / Wd);
  }
  const int m0 = by * BM;
  const int n0 = bx * BN;
  const int wr = w >> 1, wc = w & 1;
  const int lm = lane & 15, quad = lane >> 4;

  f32x4 acc[AM][AN];
  #pragma unroll
  for (int i = 0; i < AM; ++i)
    #pragma unroll
    for (int j = 0; j < AN; ++j) acc[i][j] = (f32x4){0.f, 0.f, 0.f, 0.f};

  // staging lane map + slot swizzle (write side, applied to GLOBAL source col)
  const int slot = lane & (SLOTS - 1);
  const int sr   = lane / SLOTS;     // row within this wave's RPC-row chunk
  const int swz  = (BK == 32) ? ((sr >> 1) & 3) : (sr & 7);
  const int scol = (slot ^ swz) << 3;  // shorts
  // read-side swizzle (row == lm mod 16; chunk bases are slot-period aligned)
  const int xv   = (BK == 32) ? ((lm >> 1) & 3) : (lm & 7);
  const bf16* Ab = A + aOff;
  const bf16* Bb = W + bOff;

  auto stage = [&](int buf, int k0) {
    #pragma unroll
    for (int t = 0; t < (BM * BK) / 2048; ++t) {
      const int row = w * (BM / 4) + t * RPC;
      gload_lds16(Ab + (long long)(m0 + row + sr) * lda + k0 + scol, &As[buf][row * BK]);
    }
    #pragma unroll
    for (int t = 0; t < (BN * BK) / 2048; ++t) {
      const int row = w * (BN / 4) + t * RPC;
      gload_lds16(Bb + (long long)(n0 + row + sr) * ldb + k0 + scol, &Bs[buf][row * BK]);
    }
  };
  auto compute = [&](int buf) {
    #pragma unroll
    for (int kk = 0; kk < KK; ++kk) {
      const int cb = ((kk * 4 + quad) ^ xv) << 3;   // swizzled 16B slot, shorts
      short8 af[AM], bfr[AN];
      #pragma unroll
      for (int i = 0; i < AM; ++i)
        af[i] = *(const short8*)&As[buf][(wr * WTM + i * 16 + lm) * BK + cb];
      #pragma unroll
      for (int j = 0; j < AN; ++j)
        bfr[j] = *(const short8*)&Bs[buf][(wc * WTN + j * 16 + lm) * BK + cb];
      #pragma unroll
      for (int i = 0; i < AM; ++i)
        #pragma unroll
        for (int j = 0; j < AN; ++j)
          acc[i][j] = __builtin_amdgcn_mfma_f32_16x16x32_bf16(af[i], bfr[j], acc[i][j], 0, 0, 0);
    }
  };

  stage(0, 0);
  int cur = 0;
  for (int k0 = BK; k0 < K; k0 += BK) {
    stage(cur ^ 1, k0);          // prefetch into idle buffer (stays in flight)
    vm_wait<LPW>();              // only the PREVIOUS stage's loads must land
    bar();                       // publish them to all waves
    compute(cur);
    bar();                       // all waves done reading cur before overwrite
    cur ^= 1;
  }
  vm_wait<0>();                  // last tile's loads
  bar();
  compute(cur);

  #pragma unroll
  for (int i = 0; i < AM; ++i) {
    #pragma unroll
    for (int j = 0; j < AN; ++j) {
      const int n = n0 + wc * WTN + j * 16 + lm;
      const float bj = BIAS ? bias[n] : 0.f;
      #pragma unroll
      for (int rr = 0; rr < 4; ++rr) {
        const int m = m0 + wr * WTM + i * 16 + quad * 4 + rr;
        float v = acc[i][j][rr] * scale + bj;
        if (RELU) v = fmaxf(v, 0.f);
        const long long co = cOff + (long long)m * ldc + n;
        if (OUTF32) ((float*)C)[co] = v;
        else        ((bf16*)C)[co] = f2b(v);
      }
    }
  }
}

// ---------------------------------------------------------------------------
// Fused flash attention (dense MHA): per (q-tile of 128, b, h) block.
// Swapped QK^T: st = mfma(K_frag, Q_frag) -> S^T fragments with q = lane&15,
// kv = (lane>>4)*4+reg (+16*i). Online softmax per q-col needs only 2
// shfl_xor (over quads). P^T bf16 B-frags built in-register via shfl.
// K staged from qkv, V^T staged from Vt (precomputed transpose), both via
// global_load_lds w/ the verified XOR slot swizzle; double-buffered LDS with
// the same counted-vmcnt 2-barrier protocol as mfma_gemm.
// grid (NS/128, NB*NH), 256 threads.
// ---------------------------------------------------------------------------
__global__ __launch_bounds__(256) void attn_kernel(
    const bf16* __restrict__ qkv,   // [B][S][3*ND]
    const bf16* __restrict__ Vt,    // [B*H][NDH][NS]
    bf16* __restrict__ ctx)         // [B][S][ND]
{
  __shared__ short smem[2][2][64 * 64];   // [buf][K|V][4096] = 32 KB
  const int tid = threadIdx.x, lane = tid & 63, w = tid >> 6;
  const int lm = lane & 15, quad = lane >> 4;
  const int z = blockIdx.y, b = z >> 4, h = z & 15;
  const int q0 = blockIdx.x * 128;
  const bf16* Qb = qkv + (long long)b * NS * 3072 + h * 64;
  const bf16* Kb = Qb + ND;
  const bf16* Vb = Vt + (long long)z * (NDH * NS);

  // Q B-frags [j][kk]: col q = q0 + w*32 + j*16 + lm, k(d) = kk*32 + quad*8 + e
  short8 qf[2][2];
  #pragma unroll
  for (int j = 0; j < 2; ++j)
    #pragma unroll
    for (int kk = 0; kk < 2; ++kk)
      qf[j][kk] = *(const short8*)(Qb + (long long)(q0 + w * 32 + j * 16 + lm) * 3072
                                      + kk * 32 + quad * 8);

  // staging map (8 slots of 16B per 64-elem row; 8 rows per issue per wave)
  const int slot = lane & 7, sr = lane >> 3;
  const int scol = (slot ^ sr) << 3;      // shorts; involution with read side

  auto stage = [&](int buf, int t) {
    #pragma unroll
    for (int u = 0; u < 2; ++u) {
      const int row = w * 16 + u * 8;     // kv row within tile
      gload_lds16(Kb + (long long)(t * 64 + row + sr) * 3072 + scol,
                  &smem[buf][0][row * 64]);
    }
    #pragma unroll
    for (int u = 0; u < 2; ++u) {
      const int row = w * 16 + u * 8;     // d row
      gload_lds16(Vb + (long long)(row + sr) * NS + t * 64 + scol,
                  &smem[buf][1][row * 64]);
    }
  };

  f32x4 o[4][2];                          // O^T: d-tile i, q-tile j
  #pragma unroll
  for (int i = 0; i < 4; ++i)
    #pragma unroll
    for (int j = 0; j < 2; ++j) o[i][j] = (f32x4){0.f, 0.f, 0.f, 0.f};
  float m[2] = {-1e30f, -1e30f}, l[2] = {0.f, 0.f};

  stage(0, 0);
  for (int t = 0; t < 16; ++t) {
    const int buf = t & 1;
    if (t < 15) { stage(buf ^ 1, t + 1); vm_wait<4>(); }
    else        { vm_wait<0>(); }
    bar();                                // tile t's loads visible to all

    // --- S^T = (K @ Q^T)/8 : st[i][j], i = kv-tile, j = q-tile
    f32x4 st[4][2];
    #pragma unroll
    for (int i = 0; i < 4; ++i)
      #pragma unroll
      for (int j = 0; j < 2; ++j) st[i][j] = (f32x4){0.f, 0.f, 0.f, 0.f};
    #pragma unroll
    for (int kk = 0; kk < 2; ++kk) {
      const int cb = ((kk * 4 + quad) ^ (lm & 7)) << 3;
      short8 ka[4];
      #pragma unroll
      for (int i = 0; i < 4; ++i)
        ka[i] = *(const short8*)&smem[buf][0][(i * 16 + lm) * 64 + cb];
      #pragma unroll
      for (int i = 0; i < 4; ++i)
        #pragma unroll
        for (int j = 0; j < 2; ++j)
          st[i][j] = __builtin_amdgcn_mfma_f32_16x16x32_bf16(ka[i], qf[j][kk], st[i][j], 0, 0, 0);
    }

    // --- online softmax per q-col (j); kv spread over 16 regs x 4 quads
    #pragma unroll
    for (int j = 0; j < 2; ++j) {
      float pm = -1e30f;
      #pragma unroll
      for (int i = 0; i < 4; ++i)
        #pragma unroll
        for (int r = 0; r < 4; ++r) {
          st[i][j][r] *= 0.125f;
          pm = fmaxf(pm, st[i][j][r]);
        }
      pm = fmaxf(pm, __shfl_xor(pm, 16, 64));
      pm = fmaxf(pm, __shfl_xor(pm, 32, 64));
      const float mn = fmaxf(m[j], pm);
      const float sc = __expf(m[j] - mn);
      float ps = 0.f;
      #pragma unroll
      for (int i = 0; i < 4; ++i)
        #pragma unroll
        for (int r = 0; r < 4; ++r) {
          const float e = __expf(st[i][j][r] - mn);
          st[i][j][r] = e;                 // st now holds P^T
          ps += e;
        }
      ps += __shfl_xor(ps, 16, 64);
      ps += __shfl_xor(ps, 32, 64);
      l[j] = l[j] * sc + ps;
      m[j] = mn;
      #pragma unroll
      for (int i = 0; i < 4; ++i)
        #pragma unroll
        for (int r = 0; r < 4; ++r) o[i][j][r] *= sc;
    }

    // --- pack P^T to bf16 pairs: u0 = (r0,r1), u1 = (r2,r3)
    unsigned u0[4][2], u1[4][2];
    #pragma unroll
    for (int i = 0; i < 4; ++i)
      #pragma unroll
      for (int j = 0; j < 2; ++j) {
        u0[i][j] = (unsigned)bfbits(st[i][j][0]) | ((unsigned)bfbits(st[i][j][1]) << 16);
        u1[i][j] = (unsigned)bfbits(st[i][j][2]) | ((unsigned)bfbits(st[i][j][3]) << 16);
      }
    // target frag (kk,j) elem e: kv = kk*32+quad*8+e comes from
    //   i_src = kk*2 + (quad>>1), src lane = ((quad&1)*2 + (e>>2))*16 + lm, r = e&3
    const int s0l = ((quad & 1) * 2) * 16 + lm;
    const int s1l = s0l + 16;
    const bool hi = (quad >> 1) != 0;

    // --- O^T += V^T @ P^T
    #pragma unroll
    for (int kk = 0; kk < 2; ++kk) {
      short8 pf[2];
      #pragma unroll
      for (int j = 0; j < 2; ++j) {
        const unsigned a0 = __shfl(u0[kk * 2][j],     s0l, 64);
        const unsigned a1 = __shfl(u1[kk * 2][j],     s0l, 64);
        const unsigned b0 = __shfl(u0[kk * 2 + 1][j], s0l, 64);
        const unsigned b1 = __shfl(u1[kk * 2 + 1][j], s0l, 64);
        const unsigned c0 = __shfl(u0[kk * 2][j],     s1l, 64);
        const unsigned c1 = __shfl(u1[kk * 2][j],     s1l, 64);
        const unsigned d0 = __shfl(u0[kk * 2 + 1][j], s1l, 64);
        const unsigned d1 = __shfl(u1[kk * 2 + 1][j], s1l, 64);
        union { uint4 u; short8 s; } cv;
        cv.u.x = hi ? b0 : a0; cv.u.y = hi ? b1 : a1;
        cv.u.z = hi ? d0 : c0; cv.u.w = hi ? d1 : c1;
        pf[j] = cv.s;
      }
      const int cb = ((kk * 4 + quad) ^ (lm & 7)) << 3;
      short8 va[4];
      #pragma unroll
      for (int i = 0; i < 4; ++i)
        va[i] = *(const short8*)&smem[buf][1][(i * 16 + lm) * 64 + cb];
      #pragma unroll
      for (int i = 0; i < 4; ++i)
        #pragma unroll
        for (int j = 0; j < 2; ++j)
          o[i][j] = __builtin_amdgcn_mfma_f32_16x16x32_bf16(va[i], pf[j], o[i][j], 0, 0, 0);
    }
    bar();   // all waves done reading buf before next overwrite / epilogue
  }

  // --- epilogue: normalize, transpose O^T -> O through LDS, coalesced store
  short (*OL)[72] = (short(*)[72])&smem[0][0][0];   // 128 x 72 = 18.4 KB
  #pragma unroll
  for (int j = 0; j < 2; ++j) {
    const float inv = 1.f / l[j];
    #pragma unroll
    for (int i = 0; i < 4; ++i) {
      uint2 u;
      u.x = (unsigned)bfbits(o[i][j][0] * inv) | ((unsigned)bfbits(o[i][j][1] * inv) << 16);
      u.y = (unsigned)bfbits(o[i][j][2] * inv) | ((unsigned)bfbits(o[i][j][3] * inv) << 16);
      *(uint2*)&OL[w * 32 + j * 16 + lm][i * 16 + quad * 4] = u;
    }
  }
  __syncthreads();
  {
    const int q = tid >> 1, c = (tid & 1) * 32;
    const uint4 r0 = *(const uint4*)&OL[q][c];
    const uint4 r1 = *(const uint4*)&OL[q][c + 8];
    const uint4 r2 = *(const uint4*)&OL[q][c + 16];
    const uint4 r3 = *(const uint4*)&OL[q][c + 24];
    bf16* dst = ctx + ((long long)(b * NS + q0 + q)) * 1024 + h * 64 + c;
    ((uint4*)dst)[0] = r0; ((uint4*)dst)[1] = r1;
    ((uint4*)dst)[2] = r2; ((uint4*)dst)[3] = r3;
  }
}

// ---------------------------------------------------------------------------
// All-batch: Vt[b*16+h][d][s] = qkv[b][s][2048 + h*64 + d]  (64x64 transpose)
// ---------------------------------------------------------------------------
__global__ __launch_bounds__(256) void transpose_v_kernel(
    const bf16* __restrict__ qkv, bf16* __restrict__ Vt) {
  __shared__ short T[64][72];
  const int tid = threadIdx.x;
  const int h = blockIdx.y;
  const int b = blockIdx.z;
  const int s0 = blockIdx.x * 64;
  const bf16* src = qkv + ((long long)b * NS + s0) * 3072 + 2 * ND + h * 64;
  {
    const int s = tid >> 2, c = (tid & 3) * 16;
    const uint4 a0 = *(const uint4*)(src + (long long)s * 3072 + c);
    const uint4 a1 = *(const uint4*)(src + (long long)s * 3072 + c + 8);
    *(uint4*)&T[s][c] = a0; *(uint4*)&T[s][c + 8] = a1;
  }
  __syncthreads();
  {
    const int d = tid >> 2, c = (tid & 3) * 16;
    unsigned wds[8];
    #pragma unroll
    for (int u = 0; u < 8; ++u) {
      const unsigned lo = (unsigned short)T[c + 2 * u][d];
      const unsigned hi = (unsigned short)T[c + 2 * u + 1][d];
      wds[u] = lo | (hi << 16);
    }
    bf16* dst = Vt + (long long)(b * NH + h) * (NDH * NS) + (long long)d * NS + s0 + c;
    uint4 o0, o1;
    o0.x = wds[0]; o0.y = wds[1]; o0.z = wds[2]; o0.w = wds[3];
    o1.x = wds[4]; o1.y = wds[5]; o1.z = wds[6]; o1.w = wds[7];
    ((uint4*)dst)[0] = o0; ((uint4*)dst)[1] = o1;
  }
}

// ---------------------------------------------------------------------------
// Batched 1024x1024 bf16 transpose: dst[b][d][s] = src[b][s][d]
// ---------------------------------------------------------------------------
__global__ __launch_bounds__(256) void transpose_sq_kernel(
    const bf16* __restrict__ src, bf16* __restrict__ dst) {
  __shared__ short T[64][72];
  const int tid = threadIdx.x;
  const int b = blockIdx.z;
  const int s0 = blockIdx.x * 64, d0 = blockIdx.y * 64;
  const bf16* sp = src + ((long long)b * NS + s0) * ND + d0;
  {
    const int s = tid >> 2, c = (tid & 3) * 16;
    const uint4 a0 = *(const uint4*)(sp + (long long)s * ND + c);
    const uint4 a1 = *(const uint4*)(sp + (long long)s * ND + c + 8);
    *(uint4*)&T[s][c] = a0; *(uint4*)&T[s][c + 8] = a1;
  }
  __syncthreads();
  {
    const int d = tid >> 2, c = (tid & 3) * 16;
    unsigned wds[8];
    #pragma unroll
    for (int u = 0; u < 8; ++u) {
      const unsigned lo = (unsigned short)T[c + 2 * u][d];
      const unsigned hi = (unsigned short)T[c + 2 * u + 1][d];
      wds[u] = lo | (hi << 16);
    }
    bf16* dp = dst + ((long long)b * ND + d0 + d) * NS + s0 + c;
    uint4 o0, o1;
    o0.x = wds[0]; o0.y = wds[1]; o0.z = wds[2]; o0.w = wds[3];
    o1.x = wds[4]; o1.y = wds[5]; o1.z = wds[6]; o1.w = wds[7];
    ((uint4*)dp)[0] = o0; ((uint4*)dp)[1] = o1;
  }
}

// ---------------------------------------------------------------------------
// Sparse top-k selection from precomputed fp32 scores S[row][1024].
// One WAVE per row (4 rows/block); wave-local radix select.
// ---------------------------------------------------------------------------
__global__ __launch_bounds__(256) void sparse_select_kernel(
    const float* __restrict__ S, bf16* __restrict__ aw)
{
  __shared__ unsigned hist[4][256];
  const int tid = threadIdx.x;
  const int lane = tid & 63;
  const int wv = tid >> 6;
  const long long row = (long long)blockIdx.x * 4 + wv;

  float sv[16];
  const float* sp = S + row * 1024 + lane * 16;
  #pragma unroll
  for (int c = 0; c < 4; ++c) {
    const float4 v = ((const float4*)sp)[c];
    sv[4*c] = v.x; sv[4*c+1] = v.y; sv[4*c+2] = v.z; sv[4*c+3] = v.w;
  }
  unsigned key[16];
  #pragma unroll
  for (int j = 0; j < 16; ++j) {
    const unsigned u = __float_as_uint(sv[j]);
    key[j] = (u & 0x80000000u) ? ~u : (u | 0x80000000u);  // order-preserving
  }

  unsigned pref = 0u;
  int need = NTOPK;
  #pragma unroll
  for (int p = 3; p >= 0; --p) {
    *(uint4*)&hist[wv][lane * 4] = (uint4){0u, 0u, 0u, 0u};
    __syncthreads();
    const int sh = (p + 1) * 8;
    #pragma unroll
    for (int j = 0; j < 16; ++j) {
      const bool part = (p == 3) || ((key[j] >> sh) == pref);
      if (part) atomicAdd(&hist[wv][(key[j] >> (p * 8)) & 255u], 1u);
    }
    __syncthreads();
    const unsigned h0 = hist[wv][4*lane],     h1 = hist[wv][4*lane + 1];
    const unsigned h2 = hist[wv][4*lane + 2], h3 = hist[wv][4*lane + 3];
    const unsigned s3 = h3, s2 = h2 + s3, s1 = h1 + s2, s0 = h0 + s1;
    unsigned sum = s0;                      // suffix sum over lanes >= lane
    #pragma unroll
    for (int d2 = 1; d2 < 64; d2 <<= 1) {
      const unsigned t = __shfl_down(sum, d2, 64);
      if (lane < 64 - d2) sum += t;
    }
    const unsigned above = sum - s0;
    const unsigned cum[4]  = {above + s0, above + s1, above + s2, above + s3};
    const unsigned next[4] = {above + s1, above + s2, above + s3, above};
    unsigned candPref = 0u; int candNeed = 0; bool has = false;
    #pragma unroll
    for (int i = 0; i < 4; ++i) {
      if ((int)cum[i] >= need && (int)next[i] < need) {
        has = true;
        candPref = (pref << 8) | (unsigned)(4 * lane + i);
        candNeed = need - (int)next[i];
      }
    }
    const unsigned long long m = __ballot(has);
    const int srcLane = (int)(__ffsll((long long)m) - 1);
    pref = (unsigned)__shfl((int)candPref, srcLane, 64);
    need = __shfl(candNeed, srcLane, 64);
  }

  const unsigned T = pref;                  // 204th-largest key
  const unsigned tb = (T & 0x80000000u) ? (T ^ 0x80000000u) : ~T;
  const float thr = __uint_as_float(tb);

  float wvv[16];
  float psTop = 0.f, psAll = 0.f;
  #pragma unroll
  for (int j = 0; j < 16; ++j) {
    const float e = __expf(sv[j] - thr);
    psAll += e;
    const float wt = (key[j] >= T) ? e : 0.f;
    psTop += wt;
    wvv[j] = wt;
  }
  #pragma unroll
  for (int s = 1; s < 64; s <<= 1) {
    psTop += __shfl_xor(psTop, s, 64);
    psAll += __shfl_xor(psAll, s, 64);
  }
  const float inv = 1.f / (psTop + 1e-9f * psAll);

  uint4 o0, o1;
  o0.x = (unsigned)bfbits(wvv[0]*inv)  | ((unsigned)bfbits(wvv[1]*inv)  << 16);
  o0.y = (unsigned)bfbits(wvv[2]*inv)  | ((unsigned)bfbits(wvv[3]*inv)  << 16);
  o0.z = (unsigned)bfbits(wvv[4]*inv)  | ((unsigned)bfbits(wvv[5]*inv)  << 16);
  o0.w = (unsigned)bfbits(wvv[6]*inv)  | ((unsigned)bfbits(wvv[7]*inv)  << 16);
  o1.x = (unsigned)bfbits(wvv[8]*inv)  | ((unsigned)bfbits(wvv[9]*inv)  << 16);
  o1.y = (unsigned)bfbits(wvv[10]*inv) | ((unsigned)bfbits(wvv[11]*inv) << 16);
  o1.z = (unsigned)bfbits(wvv[12]*inv) | ((unsigned)bfbits(wvv[13]*inv) << 16);
  o1.w = (unsigned)bfbits(wvv[14]*inv) | ((unsigned)bfbits(wvv[15]*inv) << 16);
  bf16* op = aw + row * 1024 + lane * 16;
  ((uint4*)op)[0] = o0; ((uint4*)op)[1] = o1;
}

// ---------------------------------------------------------------------------
// fused = sig*dense + (1-sig)*sparse ; x1 = LN1(src + fused)  (bf16 out)
// ---------------------------------------------------------------------------
__global__ __launch_bounds__(256) void fuse_ln1_kernel(
    const float* __restrict__ src, const bf16* __restrict__ dense,
    const bf16* __restrict__ sparse, const float* __restrict__ lam,
    const float* __restrict__ g, const float* __restrict__ beta,
    bf16* __restrict__ x1)
{
  __shared__ float y[ND];
  __shared__ float rbuf[256];
  const int tid = threadIdx.x;
  const size_t base = (size_t)blockIdx.x * ND;
  const float sig = 1.f / (1.f + __expf(-lam[0]));
  const float c1 = 1.f - sig;
  float s1 = 0.f, s2 = 0.f;
  #pragma unroll
  for (int j = 0; j < 4; ++j) {
    const int i = tid + (j << 8);
    const float v = src[base + i] + sig * b2f(dense[base + i]) + c1 * b2f(sparse[base + i]);
    y[i] = v; s1 += v; s2 += v * v;
  }
  const float sum1 = block_sum_256(s1, rbuf, tid);
  const float sum2 = block_sum_256(s2, rbuf, tid);
  const float mean = sum1 * (1.f / ND);
  const float var  = sum2 * (1.f / ND) - mean * mean;
  const float rstd = rsqrtf(var + 1e-5f);
  #pragma unroll
  for (int j = 0; j < 4; ++j) {
    const int i = tid + (j << 8);
    x1[base + i] = f2b((y[i] - mean) * rstd * g[i] + beta[i]);
  }
}

// out = LN2(x1 + ff)  (fp32 out; ff is bf16)
__global__ __launch_bounds__(256) void ln2_kernel(
    const bf16* __restrict__ x1, const bf16* __restrict__ ff,
    const float* __restrict__ g, const float* __restrict__ beta,
    float* __restrict__ outp)
{
  __shared__ float y[ND];
  __shared__ float rbuf[256];
  const int tid = threadIdx.x;
  const size_t base = (size_t)blockIdx.x * ND;
  float s1 = 0.f, s2 = 0.f;
  #pragma unroll
  for (int j = 0; j < 4; ++j) {
    const int i = tid + (j << 8);
    const float v = b2f(x1[base + i]) + b2f(ff[base + i]);
    y[i] = v; s1 += v; s2 += v * v;
  }
  const float sum1 = block_sum_256(s1, rbuf, tid);
  const float sum2 = block_sum_256(s2, rbuf, tid);
  const float mean = sum1 * (1.f / ND);
  const float var  = sum2 * (1.f / ND) - mean * mean;
  const float rstd = rsqrtf(var + 1e-5f);
  #pragma unroll
  for (int j = 0; j < 4; ++j) {
    const int i = tid + (j << 8);
    outp[base + i] = (y[i] - mean) * rstd * g[i] + beta[i];
  }
}

// ---------------------------------------------------------------------------
extern "C" void kernel_launch(void* const* d_in, const int* in_sizes, int n_in,
                              void* d_out, int out_size, void* d_ws, size_t ws_size,
                              hipStream_t stream)
{
  const float* src        = (const float*)d_in[0];
  const float* in_proj_w  = (const float*)d_in[1];
  const float* in_proj_b  = (const float*)d_in[2];
  const float* out_proj_w = (const float*)d_in[3];
  const float* out_proj_b = (const float*)d_in[4];
  const float* Qp_w  = (const float*)d_in[5];
  const float* Qp_b  = (const float*)d_in[6];
  const float* Kp_w  = (const float*)d_in[7];
  const float* Kp_b  = (const float*)d_in[8];
  const float* Vp_w  = (const float*)d_in[9];
  const float* Vp_b  = (const float*)d_in[10];
  const float* lam   = (const float*)d_in[11];
  const float* ff1_w = (const float*)d_in[12];
  const float* ff1_b = (const float*)d_in[13];
  const float* ff2_w = (const float*)d_in[14];
  const float* ff2_b = (const float*)d_in[15];
  const float* ln1_g = (const float*)d_in[16];
  const float* ln1_b = (const float*)d_in[17];
  const float* ln2_g = (const float*)d_in[18];
  const float* ln2_b = (const float*)d_in[19];
  (void)in_sizes; (void)n_in; (void)out_size; (void)ws_size;

  // --------- workspace layout (offsets IDENTICAL to the proven layout;
  // Vt_all reuses the old S_b slot)
  char* ws = (char*)d_ws;
  size_t off = 0;
  auto take = [&](size_t bytes) -> void* {
    void* p = ws + off; off += (bytes + 255) & ~(size_t)255; return p;
  };
  bf16*  src_bf  = (bf16*) take((size_t)NM * ND * 2);          //  8.4 MB
  bf16*  w_qkv   = (bf16*) take((size_t)3 * ND * ND * 2);      //  6.3 MB
  bf16*  w_out   = (bf16*) take((size_t)ND * ND * 2);          //  2.1 MB
  bf16*  w_vp    = (bf16*) take((size_t)ND * ND * 2);          //  2.1 MB
  bf16*  w_ff1   = (bf16*) take((size_t)NDFF * ND * 2);        //  8.4 MB
  bf16*  w_ff2   = (bf16*) take((size_t)ND * NDFF * 2);        //  8.4 MB
  bf16*  w_qk    = (bf16*) take((size_t)128 * ND * 2);         //  0.26 MB
  float* bias_qk = (float*)take(128 * 4);
  const size_t mark = off;                                     // reuse point
  bf16*  qkv     = (bf16*) take((size_t)NM * 3 * ND * 2);      // 25.2 MB [dead after attn]
  bf16*  Vt_all  = (bf16*) take((size_t)NH * NS * NS * 2);     // slot 33.5 MB (uses 8.4) [dead after attn]
  bf16*  Vt_old  = (bf16*) take((size_t)NH * NDH * NS * 2);    //  2.1 MB [unused slot, keeps offsets]
  bf16*  ctx     = (bf16*) take((size_t)NM * ND * 2);          //  8.4 MB [dead after step 3]
  bf16*  dense   = (bf16*) take((size_t)NM * ND * 2);          //  8.4 MB
  bf16*  QKs_bf  = (bf16*) take((size_t)NM * 128 * 2);         //  1.05 MB
  bf16*  Vsp     = (bf16*) take((size_t)NM * ND * 2);          //  8.4 MB
  bf16*  sparse  = (bf16*) take((size_t)NM * ND * 2);          //  8.4 MB
  (void)Vt_old;
  // aliases into dead regions (qkv+Vt_all dead after the attention):
  bf16*  x1    = (bf16*)(ws + mark);                                       // [0, 8.4M)
  bf16*  h1    = (bf16*)(ws + mark + (size_t)NM * ND * 2);                 // [8.4, 42.0M)
  bf16*  ffout = (bf16*)(ws + mark + (size_t)NM * ND * 2 + (size_t)NM * NDFF * 2); // [42.0, 50.4M)
  bf16*  aw    = (bf16*)(ws + mark + 2 * (size_t)NM * ND * 2 + (size_t)NM * NDFF * 2); // [50.4, 58.8M)
  float* S_sp  = (float*)(ws + mark + (size_t)NM * ND * 2);    // [8.4, 25.2M): written 4b,
                                                               // read 6a, dead before h1
  bf16*  Vsp_t = (bf16*)ctx;  // ctx dead after step 3

  const dim3 blk(256);
  // 0. fp32 -> bf16 conversions, one fused launch (6 regions, 17408 blocks)
  {
    CastArgs a;
    a.in[0] = src;        a.out[0] = src_bf;  // 4096 blocks
    a.in[1] = in_proj_w;  a.out[1] = w_qkv;   // 3072
    a.in[2] = out_proj_w; a.out[2] = w_out;   // 1024
    a.in[3] = Vp_w;       a.out[3] = w_vp;    // 1024
    a.in[4] = ff1_w;      a.out[4] = w_ff1;   // 4096
    a.in[5] = ff2_w;      a.out[5] = w_ff2;   // 4096
    a.end[0] = 4096; a.end[1] = 7168; a.end[2] = 8192;
    a.end[3] = 9216; a.end[4] = 13312; a.end[5] = 17408;
    cast6_kernel<<<dim3(17408), blk, 0, stream>>>(a);
  }
  pack_qk_kernel<<<dim3(128), blk, 0, stream>>>(Qp_w, Kp_w, Qp_b, Kp_b, w_qk, bias_qk);

  // 1. qkv = src @ in_proj^T + b   [4096,3072] bf16  (768 blocks)
  mfma_gemm<128,128,32,1,0,0><<<dim3(3*ND/128, NM/128, 1), blk, 0, stream>>>(
      src_bf, w_qkv, in_proj_b, qkv, ND, ND, ND, 3*ND, 0,0, 0,0, 0,0, 1.f);

  // 2. dense MHA: V transpose (all batches) + fused flash attention
  transpose_v_kernel<<<dim3(NS/64, NH, NB), blk, 0, stream>>>(qkv, Vt_all);
  attn_kernel<<<dim3(NS/128, NB*NH), blk, 0, stream>>>(qkv, Vt_all, ctx);

  // 3. dense_output = ctx @ out_proj^T + b  (bf16; 128x64xBK64 -> 512 blocks)
  mfma_gemm<128,64,64,1,0,0><<<dim3(ND/64, NM/128, 1), blk, 0, stream>>>(
      ctx, w_out, out_proj_b, dense, ND, ND, ND, ND, 0,0, 0,0, 0,0, 1.f);
  // 4. QKs_bf = src @ [Qp;Kp]^T + b  (bf16 [4096][128]; 64 blocks)
  mfma_gemm<128,64,64,1,0,0><<<dim3(2, NM/128, 1), blk, 0, stream>>>(
      src_bf, w_qk, bias_qk, QKs_bf, ND, ND, ND, 128, 0,0, 0,0, 0,0, 1.f);
  // 4b. S_sp[b] = (Qs Ks^T)/8  fp32, batched over b (single K-tile at BK=64)
  mfma_gemm<128,64,64,0,0,1><<<dim3(NS/64, NS/128, NB), blk, 0, stream>>>(
      QKs_bf, QKs_bf + 64, nullptr, S_sp, 64, 128, 128, NS,
      0, (long long)NS*128, 0, (long long)NS*128, 0, (long long)NS*NS, 0.125f);
  // 5. Vsp = src @ Vp^T + b  (bf16; 512 blocks)
  mfma_gemm<128,64,64,1,0,0><<<dim3(ND/64, NM/128, 1), blk, 0, stream>>>(
      src_bf, w_vp, Vp_b, Vsp, ND, ND, ND, ND, 0,0, 0,0, 0,0, 1.f);
  // 5b. Vsp_t[b][d][s] = Vsp[b][s][d]   (ctx slot reused)
  transpose_sq_kernel<<<dim3(NS/64, ND/64, NB), blk, 0, stream>>>(Vsp, Vsp_t);
  // 6a. top-k select + normalized weights -> aw (bf16), one wave per row
  sparse_select_kernel<<<dim3(NM/4), blk, 0, stream>>>(S_sp, aw);
  // 6b. sparse = aw @ Vsp^T  (batched per b; 512 blocks)
  mfma_gemm<128,64,64,0,0,0><<<dim3(ND/64, NS/128, NB), blk, 0, stream>>>(
      aw, Vsp_t, nullptr, sparse, NS, NS, NS, ND,
      0, (long long)NS*ND, 0, (long long)ND*NS, 0, (long long)NS*ND, 1.f);
  // 7. fuse + residual + LN1 -> x1 (bf16)  [qkv/Vt_all dead; x1 aliases them]
  fuse_ln1_kernel<<<dim3(NM), blk, 0, stream>>>(src, dense, sparse, lam, ln1_g, ln1_b, x1);
  // 8. h1 = relu(x1 @ ff1^T + b)  (bf16; 1024 blocks)
  mfma_gemm<128,128,32,1,1,0><<<dim3(NDFF/128, NM/128, 1), blk, 0, stream>>>(
      x1, w_ff1, ff1_b, h1, ND, ND, ND, NDFF, 0,0, 0,0, 0,0, 1.f);
  // 9. ff = h1 @ ff2^T + b  (bf16; 128x64xBK64 -> 512 blocks)
  mfma_gemm<128,64,64,1,0,0><<<dim3(ND/64, NM/128, 1), blk, 0, stream>>>(
      h1, w_ff2, ff2_b, ffout, NDFF, NDFF, NDFF, ND, 0,0, 0,0, 0,0, 1.f);
  // 10. out = LN2(x1 + ff)  (fp32)
  ln2_kernel<<<dim3(NM), blk, 0, stream>>>(x1, ffout, ln2_g, ln2_b, (float*)d_out);
}